// Round 7
// baseline (250.147 us; speedup 1.0000x reference)
//
#include <hip/hip_runtime.h>
#include <hip/hip_bf16.h>

#define HIDDEN 1024
#define NH 16
#define BATCH 2
#define SEQ 2048

typedef __attribute__((ext_vector_type(8))) short bf16x8;
typedef __attribute__((ext_vector_type(4))) float f32x4;
typedef __attribute__((ext_vector_type(2))) uint uint2v;

__device__ __forceinline__ ushort f2bf(float f) {
    __hip_bfloat16 h = __float2bfloat16(f);
    return *reinterpret_cast<ushort*>(&h);
}
__device__ __forceinline__ float fexp2(float x) {
#if __has_builtin(__builtin_amdgcn_exp2f)
    return __builtin_amdgcn_exp2f(x);
#else
    return exp2f(x);
#endif
}
// pack trunc-bf16(a) low, trunc-bf16(b) high (1 v_perm)
__device__ __forceinline__ uint pack_bf_trunc(float a, float b) {
    return __builtin_amdgcn_perm(__float_as_uint(b), __float_as_uint(a), 0x07060302u);
}

// butterfly: (A,B) -> A' = [a0,b0,a1,b1], B' = [a2,b2,a3,b3] (16-lane rows).
__device__ __forceinline__ void bfly(uint &a, uint &b) {
#if __has_builtin(__builtin_amdgcn_permlane16_swap)
    uint2v t = __builtin_amdgcn_permlane16_swap(a, b, false, false);
    uint2v s = __builtin_amdgcn_permlane32_swap(t[0], t[1], false, false);
    a = s[0]; b = s[1];
#else
    asm volatile("v_permlane16_swap_b32 %0, %1" : "+v"(a), "+v"(b));
    asm volatile("v_permlane32_swap_b32 %0, %1" : "+v"(a), "+v"(b));
#endif
}

// async global->LDS, 16B per lane
__device__ __forceinline__ void async_copy16(const ushort* g, ushort* l) {
    __builtin_amdgcn_global_load_lds((const __attribute__((address_space(1))) void*)g,
                                     (__attribute__((address_space(3))) void*)l,
                                     16, 0, 0);
}

// keep-alives (rule #17: prevent DCE of ablation-stubbed phases)
__device__ __forceinline__ void keep_f32x4(const f32x4 &v) {
    asm volatile("" :: "v"(v[0]), "v"(v[1]), "v"(v[2]), "v"(v[3]));
}
__device__ __forceinline__ void keep_bf16x8(const bf16x8 &h) {
    union { bf16x8 hh; uint u[4]; } cv; cv.hh = h;
    asm volatile("" :: "v"(cv.u[0]), "v"(cv.u[1]), "v"(cv.u[2]), "v"(cv.u[3]));
}

// ---------------------------------------------------------------------------
// Fused prep: [0,4096) x->bf16 | [4096,7168) Wqkv transpose | [7168,8192) Wo transpose
// ---------------------------------------------------------------------------
__global__ void prep_kernel(const float* __restrict__ x,
                            const float* __restrict__ Wqkv,
                            const float* __restrict__ Wo,
                            ushort* __restrict__ xb,
                            ushort* __restrict__ Wt,
                            ushort* __restrict__ WoT)
{
    __shared__ float t[32][33];
    const int bid = blockIdx.x;
    const int tid = threadIdx.x;

    if (bid < 4096) {
        int i = (bid * 256 + tid) * 4;
        float4 v = *(const float4*)(x + i);
        ushort4 w;
        w.x = f2bf(v.x); w.y = f2bf(v.y); w.z = f2bf(v.z); w.w = f2bf(v.w);
        *(ushort4*)(xb + i) = w;
        return;
    }
    const int r = tid >> 3;
    const int c = (tid & 7) * 4;
    if (bid < 7168) {
        int tt = bid - 4096;
        int k0 = (tt & 31) * 32;
        int n0 = (tt >> 5) * 32;
        const int N = 3 * HIDDEN, K = HIDDEN;
        float4 v = *(const float4*)(Wqkv + (size_t)(k0 + r) * N + n0 + c);
        t[r][c] = v.x; t[r][c + 1] = v.y; t[r][c + 2] = v.z; t[r][c + 3] = v.w;
        __syncthreads();
        ushort4 w;
        w.x = f2bf(t[c + 0][r]); w.y = f2bf(t[c + 1][r]);
        w.z = f2bf(t[c + 2][r]); w.w = f2bf(t[c + 3][r]);
        *(ushort4*)(Wt + (size_t)(n0 + r) * K + k0 + c) = w;
    } else {
        int tt = bid - 7168;
        int k0 = (tt & 31) * 32;
        int n0 = (tt >> 5) * 32;
        const int N = HIDDEN, K = HIDDEN;
        float4 v = *(const float4*)(Wo + (size_t)(k0 + r) * N + n0 + c);
        t[r][c] = v.x; t[r][c + 1] = v.y; t[r][c + 2] = v.z; t[r][c + 3] = v.w;
        __syncthreads();
        ushort4 w;
        w.x = f2bf(t[c + 0][r]); w.y = f2bf(t[c + 1][r]);
        w.z = f2bf(t[c + 2][r]); w.w = f2bf(t[c + 3][r]);
        *(ushort4*)(WoT + (size_t)(n0 + r) * K + k0 + c) = w;
    }
}

// ---------------------------------------------------------------------------
// bf16 MFMA GEMM1: qkv = x @ Wqkv^T + bias -> bf16. Q cols scaled by qscale
// (0.125*log2e -> softmax via exp2). When vt_mode, V cols (>=2048) go
// transposed + Pi-permuted into vtg[b][h][d][s'] (fused transpose_v).
// ---------------------------------------------------------------------------
__global__ __launch_bounds__(256, 3)
void gemm_mfma_bf16_kernel(const ushort* __restrict__ A,
                           const ushort* __restrict__ Bt,
                           const float* __restrict__ bias,
                           ushort* __restrict__ C, int N,
                           int qscale_cols, float qscale,
                           ushort* __restrict__ vtg, int vt_mode)
{
    constexpr int K = 1024;
    __shared__ ushort As[128 * 64];
    __shared__ ushort Bs[128 * 64];

    const int tid  = threadIdx.x;
    const int wave = tid >> 6;
    const int lane = tid & 63;
    const int l16  = lane & 15;
    const int quad = lane >> 4;
    const int wm = wave & 1, wn = wave >> 1;

    const int bm = blockIdx.y * 128;
    const int bn = blockIdx.x * 128;

    const int srow = lane >> 3;
    const int lblk = (lane & 7) ^ srow;
    const ushort* Ag = A  + (size_t)(bm + wave * 32 + srow) * K + lblk * 8;
    const ushort* Bg = Bt + (size_t)(bn + wave * 32 + srow) * K + lblk * 8;
    ushort* Asl = As + wave * 32 * 64;
    ushort* Bsl = Bs + wave * 32 * 64;

    f32x4 acc[4][4];
    #pragma unroll
    for (int i = 0; i < 4; i++)
        #pragma unroll
        for (int j = 0; j < 4; j++) acc[i][j] = (f32x4){0.f, 0.f, 0.f, 0.f};

    for (int k0 = 0; k0 < K; k0 += 64) {
        __syncthreads();
        #pragma unroll
        for (int t = 0; t < 4; t++) {
            async_copy16(Ag + (size_t)t * 8 * K + k0, Asl + t * 8 * 64);
            async_copy16(Bg + (size_t)t * 8 * K + k0, Bsl + t * 8 * 64);
        }
        __syncthreads();

        #pragma unroll
        for (int s = 0; s < 2; s++) {
            bf16x8 af[4], bfr[4];
            #pragma unroll
            for (int i = 0; i < 4; i++) {
                int m = wm * 64 + i * 16 + l16;
                int n = wn * 64 + i * 16 + l16;
                af[i]  = *(const bf16x8*)&As[m * 64 + (((s * 4 + quad) ^ (m & 7)) << 3)];
                bfr[i] = *(const bf16x8*)&Bs[n * 64 + (((s * 4 + quad) ^ (n & 7)) << 3)];
            }
            #pragma unroll
            for (int i = 0; i < 4; i++)
                #pragma unroll
                for (int j = 0; j < 4; j++)
                    acc[i][j] = __builtin_amdgcn_mfma_f32_16x16x32_bf16(af[i], bfr[j], acc[i][j], 0, 0, 0);
        }
    }

    #pragma unroll
    for (int j = 0; j < 4; j++) {
        int col = bn + wn * 64 + j * 16 + l16;
        float bv = bias[col];
        if (vt_mode && col >= 2048) {
            // V -> vtg transposed + Pi: s64 = i*16+quad*4+r; Pi(s64)=(quad*4+r)*4+i
            int dfull = col - 2048;
            int hh = dfull >> 6, dd = dfull & 63;
            int bb = bm >> 11;
            int sb = ((bm & 2047) + wm * 64) >> 6;
            ushort tmp[16];
            #pragma unroll
            for (int i = 0; i < 4; i++)
                #pragma unroll
                for (int r = 0; r < 4; r++)
                    tmp[r * 4 + i] = f2bf(acc[i][j][r] + bv);
            ushort* dst = vtg + ((size_t)((bb * NH + hh) * 64 + dd)) * SEQ
                          + sb * 64 + quad * 16;
            *(uint4*)dst = *(const uint4*)tmp;
            *(uint4*)(dst + 8) = *(const uint4*)(tmp + 8);
        } else {
            float s = (col < qscale_cols) ? qscale : 1.0f;
            #pragma unroll
            for (int i = 0; i < 4; i++) {
                int row0 = bm + wm * 64 + i * 16 + quad * 4;
                #pragma unroll
                for (int r = 0; r < 4; r++)
                    C[(size_t)(row0 + r) * N + col] = f2bf((acc[i][j][r] + bv) * s);
            }
        }
    }
}

// ---------------------------------------------------------------------------
// Output projection, single-pass bf16 MFMA: C[4096][1024]f32 = attn @ WoT^T + bo.
// ---------------------------------------------------------------------------
__global__ __launch_bounds__(256, 4)
void gemm_out_kernel(const ushort* __restrict__ A,
                     const ushort* __restrict__ Bt,
                     const float* __restrict__ bias,
                     float* __restrict__ C)
{
    constexpr int K = 1024, N = 1024;
    __shared__ ushort As[128 * 64];
    __shared__ ushort Bs[64 * 64];

    const int tid  = threadIdx.x;
    const int wave = tid >> 6;
    const int lane = tid & 63;
    const int l16  = lane & 15;
    const int quad = lane >> 4;
    const int wm = wave & 1, wn = wave >> 1;

    const int bm = blockIdx.y * 128;
    const int bn = blockIdx.x * 64;

    const int srow = lane >> 3;
    const int lblk = (lane & 7) ^ srow;
    const ushort* Ag = A  + (size_t)(bm + wave * 32 + srow) * K + lblk * 8;
    const ushort* Bg = Bt + (size_t)(bn + wave * 16 + srow) * K + lblk * 8;
    ushort* Asl = As + wave * 32 * 64;
    ushort* Bsl = Bs + wave * 16 * 64;

    f32x4 acc[4][2];
    #pragma unroll
    for (int i = 0; i < 4; i++)
        #pragma unroll
        for (int j = 0; j < 2; j++) acc[i][j] = (f32x4){0.f, 0.f, 0.f, 0.f};

    for (int k0 = 0; k0 < K; k0 += 64) {
        __syncthreads();
        #pragma unroll
        for (int t = 0; t < 4; t++)
            async_copy16(Ag + (size_t)t * 8 * K + k0, Asl + t * 8 * 64);
        #pragma unroll
        for (int t = 0; t < 2; t++)
            async_copy16(Bg + (size_t)t * 8 * K + k0, Bsl + t * 8 * 64);
        __syncthreads();

        #pragma unroll
        for (int s = 0; s < 2; s++) {
            bf16x8 af[4], bfr[2];
            #pragma unroll
            for (int i = 0; i < 4; i++) {
                int m = wm * 64 + i * 16 + l16;
                af[i] = *(const bf16x8*)&As[m * 64 + (((s * 4 + quad) ^ (m & 7)) << 3)];
            }
            #pragma unroll
            for (int j = 0; j < 2; j++) {
                int n = wn * 32 + j * 16 + l16;
                bfr[j] = *(const bf16x8*)&Bs[n * 64 + (((s * 4 + quad) ^ (n & 7)) << 3)];
            }
            #pragma unroll
            for (int i = 0; i < 4; i++)
                #pragma unroll
                for (int j = 0; j < 2; j++)
                    acc[i][j] = __builtin_amdgcn_mfma_f32_16x16x32_bf16(af[i], bfr[j], acc[i][j], 0, 0, 0);
        }
    }

    #pragma unroll
    for (int j = 0; j < 2; j++) {
        int col = bn + wn * 32 + j * 16 + l16;
        float bv = bias[col];
        #pragma unroll
        for (int i = 0; i < 4; i++) {
            int row0 = bm + wm * 64 + i * 16 + quad * 4;
            #pragma unroll
            for (int r = 0; r < 4; r++)
                C[(size_t)(row0 + r) * N + col] = acc[i][j][r] + bv;
        }
    }
}

// ---------------------------------------------------------------------------
// Flash attention ablation family (PH template). PH=4 == v12 (real output).
// PH=1: staging+barrier loop only. PH=2: +QK MFMAs (sc kept live).
// PH=3: +softmax/butterfly (ap kept live). PH=4: +PV (full, correct).
// PH<4 dispatches write garbage to the attn scratch region; the PH=4 run
// executes LAST and overwrites every output byte. Measurement round:
// marginals t2-t1 / t3-t2 / t4-t3 attribute QK / softmax / PV; t1 is the
// staging+sync floor that no phase-level optimization can beat.
// ---------------------------------------------------------------------------
template<int PH>
__global__ __launch_bounds__(256, 2)
void attn_ab_kernel(const ushort* __restrict__ qkvb,
                    const ushort* __restrict__ vtg,
                    ushort* __restrict__ attn)
{
    // ushort layout: K[2][4096] | V[2][4096] @8192  -> 32 KB
    __shared__ __align__(16) ushort smem[16384];

    const int tid  = threadIdx.x;
    const int wave = tid >> 6;
    const int lane = tid & 63;
    const int l16  = lane & 15;
    const int quad = lane >> 4;

    // XCD swizzle: xcd = bid&7 gets heads [xcd*4, xcd*4+4), all 16 qb each.
    const int obid = blockIdx.x;
    const int qb = (obid >> 3) & 15;
    const int bh = (obid & 7) * 4 + (obid >> 7);
    const int h  = bh & (NH - 1);
    const int b  = bh >> 4;

    const int qbase = qb * 128 + wave * 32;   // 32 q-rows per wave
    const int hoff  = h * 64;

    // Q fragments: 2 row-groups of 16 (used as the MFMA *B* operand)
    bf16x8 a_q[2][2];
    #pragma unroll
    for (int mg = 0; mg < 2; mg++) {
        int qrow = b * SEQ + qbase + mg * 16 + l16;
        const ushort* qp = qkvb + (size_t)qrow * 3072 + hoff + quad * 8;
        a_q[mg][0] = *(const bf16x8*)qp;
        a_q[mg][1] = *(const bf16x8*)(qp + 32);
    }

    f32x4 o[2][4];
    f32x4 lacc[2];
    #pragma unroll
    for (int mg = 0; mg < 2; mg++) {
        lacc[mg] = (f32x4){0.f, 0.f, 0.f, 0.f};
        #pragma unroll
        for (int nt = 0; nt < 4; nt++) o[mg][nt] = (f32x4){0.f, 0.f, 0.f, 0.f};
    }

    bf16x8 b_ones;
    #pragma unroll
    for (int j = 0; j < 8; j++) b_ones[j] = (short)0x3f80;

    const ushort* kvb    = qkvb + (size_t)b * SEQ * 3072;
    const ushort* vtg_bh = vtg + (size_t)((b * NH + h) * 64) * SEQ;

    const int srow8 = lane >> 3;
    const int gblk  = ((lane & 7) ^ srow8) << 3;
    const ushort* kg = kvb + (size_t)(wave * 16 + srow8) * 3072 + 1024 + hoff + gblk;
    const ushort* vg = vtg_bh + (size_t)(wave * 16 + srow8) * SEQ + gblk;

    ushort* k_dst = smem + wave * 1024;          // + c*512 + (cur<<12)
    ushort* v_dst = smem + 8192 + wave * 1024;   // + c*512 + (cur<<12)

    // prologue: stage tile 0 into buf 0; barrier drains vmcnt
    #pragma unroll
    for (int c = 0; c < 2; c++) {
        async_copy16(kg + (size_t)(c * 8) * 3072, k_dst + c * 512);
        async_copy16(vg + (size_t)(c * 8) * SEQ,  v_dst + c * 512);
    }
    __syncthreads();

    int cur = 0;
    for (int t = 0; t < 32; t++) {
        // stage tile t+1 into the other buffer (drained by end-of-iter barrier)
        if (t < 31) {
            const int k0n = (t + 1) * 64;
            #pragma unroll
            for (int c = 0; c < 2; c++) {
                async_copy16(kg + (size_t)(k0n + c * 8) * 3072,
                             k_dst + c * 512 + ((cur ^ 1) << 12));
                async_copy16(vg + (size_t)(c * 8) * SEQ + k0n,
                             v_dst + c * 512 + ((cur ^ 1) << 12));
            }
        }
        const ushort* Ks = smem + (cur << 12);
        const ushort* Vs = smem + 8192 + (cur << 12);

        f32x4 sc[2][4];
        if constexpr (PH >= 2) {
            // swapped QK^T: D[row=key-in-tile=quad*4+r][col=q=l16].
            __builtin_amdgcn_s_setprio(1);
            #pragma unroll
            for (int nt = 0; nt < 4; nt++) {
                int key = nt * 16 + l16;
                bf16x8 bk0 = *(const bf16x8*)&Ks[key * 64 + ((quad ^ (key & 7)) << 3)];
                bf16x8 bk1 = *(const bf16x8*)&Ks[key * 64 + (((4 + quad) ^ (key & 7)) << 3)];
                #pragma unroll
                for (int mg = 0; mg < 2; mg++) {
                    f32x4 a = (f32x4){0.f, 0.f, 0.f, 0.f};
                    a = __builtin_amdgcn_mfma_f32_16x16x32_bf16(bk0, a_q[mg][0], a, 0, 0, 0);
                    a = __builtin_amdgcn_mfma_f32_16x16x32_bf16(bk1, a_q[mg][1], a, 0, 0, 0);
                    sc[mg][nt] = a;
                }
            }
            __builtin_amdgcn_s_setprio(0);
            if constexpr (PH == 2) {
                #pragma unroll
                for (int mg = 0; mg < 2; mg++)
                    #pragma unroll
                    for (int nt = 0; nt < 4; nt++) keep_f32x4(sc[mg][nt]);
            }
        }

        bf16x8 ap[2][2];
        if constexpr (PH >= 3) {
            // exp2 + pack (nt0 with nt1, nt2 with nt3) + butterfly -> PV frags.
            #pragma unroll
            for (int mg = 0; mg < 2; mg++) {
                uint w00 = pack_bf_trunc(fexp2(sc[mg][0][0]), fexp2(sc[mg][1][0]));
                uint w01 = pack_bf_trunc(fexp2(sc[mg][0][1]), fexp2(sc[mg][1][1]));
                uint w02 = pack_bf_trunc(fexp2(sc[mg][0][2]), fexp2(sc[mg][1][2]));
                uint w03 = pack_bf_trunc(fexp2(sc[mg][0][3]), fexp2(sc[mg][1][3]));
                uint w10 = pack_bf_trunc(fexp2(sc[mg][2][0]), fexp2(sc[mg][3][0]));
                uint w11 = pack_bf_trunc(fexp2(sc[mg][2][1]), fexp2(sc[mg][3][1]));
                uint w12 = pack_bf_trunc(fexp2(sc[mg][2][2]), fexp2(sc[mg][3][2]));
                uint w13 = pack_bf_trunc(fexp2(sc[mg][2][3]), fexp2(sc[mg][3][3]));
                bfly(w00, w02);
                bfly(w01, w03);
                bfly(w10, w12);
                bfly(w11, w13);
                union { uint u[4]; bf16x8 h; } u0, u1;
                u0.u[0] = w00; u0.u[1] = w10; u0.u[2] = w01; u0.u[3] = w11;
                u1.u[0] = w02; u1.u[1] = w12; u1.u[2] = w03; u1.u[3] = w13;
                ap[mg][0] = u0.h;
                ap[mg][1] = u1.h;
            }
            if constexpr (PH == 3) {
                #pragma unroll
                for (int mg = 0; mg < 2; mg++) {
                    keep_bf16x8(ap[mg][0]);
                    keep_bf16x8(ap[mg][1]);
                }
            }
        }

        if constexpr (PH >= 4) {
            // PV + l via ones-MFMA; V fragment loaded once, used by both mg
            __builtin_amdgcn_s_setprio(1);
            #pragma unroll
            for (int nt = 0; nt < 4; nt++) {
                int d = nt * 16 + l16;
                bf16x8 bv0 = *(const bf16x8*)&Vs[d * 64 + ((quad ^ (d & 7)) << 3)];
                bf16x8 bv1 = *(const bf16x8*)&Vs[d * 64 + (((4 + quad) ^ (d & 7)) << 3)];
                #pragma unroll
                for (int mg = 0; mg < 2; mg++) {
                    o[mg][nt] = __builtin_amdgcn_mfma_f32_16x16x32_bf16(ap[mg][0], bv0, o[mg][nt], 0, 0, 0);
                    o[mg][nt] = __builtin_amdgcn_mfma_f32_16x16x32_bf16(ap[mg][1], bv1, o[mg][nt], 0, 0, 0);
                }
            }
            #pragma unroll
            for (int mg = 0; mg < 2; mg++) {
                lacc[mg] = __builtin_amdgcn_mfma_f32_16x16x32_bf16(ap[mg][0], b_ones, lacc[mg], 0, 0, 0);
                lacc[mg] = __builtin_amdgcn_mfma_f32_16x16x32_bf16(ap[mg][1], b_ones, lacc[mg], 0, 0, 0);
            }
            __builtin_amdgcn_s_setprio(0);
        }

        // everyone done reading buf[cur]; tile t+1 loads drained by barrier
        __syncthreads();
        cur ^= 1;
    }

    // epilogue: per-wave, no cross-wave combine (keeps o/lacc live for PH<4)
    #pragma unroll
    for (int mg = 0; mg < 2; mg++) {
        #pragma unroll
        for (int r = 0; r < 4; r++) {
            float inv = 1.f / lacc[mg][r];
            int row = b * SEQ + qbase + mg * 16 + quad * 4 + r;
            size_t base = (size_t)row * HIDDEN + hoff + l16;
            #pragma unroll
            for (int nt = 0; nt < 4; nt++)
                attn[base + nt * 16] = f2bf(o[mg][nt][r] * inv);
        }
    }
}

// ---------------------------------------------------------------------------
// Fallback attention (no vtg workspace): barrier kernel staging K + Pi-V.
// ---------------------------------------------------------------------------
__global__ __launch_bounds__(512, 4)
void attn_mfma_fb_kernel(const ushort* __restrict__ qkvb,
                         ushort* __restrict__ attn)
{
    __shared__ __align__(16) ushort smem[34816];

    const int tid   = threadIdx.x;
    const int wave  = tid >> 6;
    const int wavel = wave & 3;
    const int kh    = wave >> 2;
    const int lane  = tid & 63;
    const int l16   = lane & 15;
    const int quad  = lane >> 4;

    const int qb = blockIdx.x & 15;
    const int bh = blockIdx.x >> 4;
    const int h  = bh & (NH - 1);
    const int b  = bh >> 4;

    const int qbase = qb * 128;
    const int hoff  = h * 64;

    ushort* KsH = smem + kh * 4096;
    ushort* VsH = smem + 8192 + kh * 4096;
    ushort* Psw = smem + 16384 + wave * 2304;

    bf16x8 a_q[2][2];
    #pragma unroll
    for (int mg = 0; mg < 2; mg++) {
        int qrow = b * SEQ + qbase + wavel * 32 + mg * 16 + l16;
        const ushort* qp = qkvb + (size_t)qrow * 3072 + hoff + quad * 8;
        a_q[mg][0] = *(const bf16x8*)qp;
        a_q[mg][1] = *(const bf16x8*)(qp + 32);
    }

    f32x4 o[2][4];
    f32x4 lacc[2];
    #pragma unroll
    for (int mg = 0; mg < 2; mg++) {
        lacc[mg] = (f32x4){0.f, 0.f, 0.f, 0.f};
        #pragma unroll
        for (int nt = 0; nt < 4; nt++) o[mg][nt] = (f32x4){0.f, 0.f, 0.f, 0.f};
    }

    bf16x8 b_ones;
    #pragma unroll
    for (int j = 0; j < 8; j++) b_ones[j] = (short)0x3f80;

    const ushort* kvb = qkvb + (size_t)b * SEQ * 3072;

    for (int t = 0; t < 16; t++) {
        const int k0 = t * 64;
        __syncthreads();
        {
            const int tl = tid & 255;
            #pragma unroll
            for (int i = 0; i < 2; i++) {
                int key = (tl >> 3) + 32 * i;
                int blk = tl & 7;
                const ushort* ksrc = kvb + (size_t)(kh * 1024 + k0 + key) * 3072 + 1024 + hoff + blk * 8;
                uint4 kv = *(const uint4*)ksrc;
                *(uint4*)&KsH[key * 64 + ((blk ^ (key & 7)) << 3)] = kv;
                uint4 vv = *(const uint4*)(ksrc + 1024);
                const ushort* vpp = (const ushort*)&vv;
                int pk_ = (key & 15) * 4 + (key >> 4);
                #pragma unroll
                for (int j = 0; j < 8; j++) {
                    int d = blk * 8 + j;
                    VsH[d * 64 + (((pk_ >> 3) ^ (d & 7)) << 3) + (pk_ & 7)] = vpp[j];
                }
            }
        }
        __syncthreads();

        f32x4 sc[2][4];
        #pragma unroll
        for (int nt = 0; nt < 4; nt++) {
            int key = nt * 16 + l16;
            bf16x8 bk0 = *(const bf16x8*)&KsH[key * 64 + ((quad ^ (key & 7)) << 3)];
            bf16x8 bk1 = *(const bf16x8*)&KsH[key * 64 + (((4 + quad) ^ (key & 7)) << 3)];
            #pragma unroll
            for (int mg = 0; mg < 2; mg++) {
                f32x4 a = (f32x4){0.f, 0.f, 0.f, 0.f};
                a = __builtin_amdgcn_mfma_f32_16x16x32_bf16(a_q[mg][0], bk0, a, 0, 0, 0);
                a = __builtin_amdgcn_mfma_f32_16x16x32_bf16(a_q[mg][1], bk1, a, 0, 0, 0);
                sc[mg][nt] = a;
            }
        }

        #pragma unroll
        for (int mg = 0; mg < 2; mg++) {
            #pragma unroll
            for (int r = 0; r < 4; r++) {
                int q = mg * 16 + quad * 4 + r;
                uint2 pk2;
                pk2.x = pack_bf_trunc(fexp2(sc[mg][0][r]), fexp2(sc[mg][1][r]));
                pk2.y = pack_bf_trunc(fexp2(sc[mg][2][r]), fexp2(sc[mg][3][r]));
                *(uint2*)&Psw[q * 72 + l16 * 4] = pk2;
            }
        }

        asm volatile("s_waitcnt lgkmcnt(0)" ::: "memory");
        bf16x8 a_p[2][2];
        #pragma unroll
        for (int mg = 0; mg < 2; mg++) {
            a_p[mg][0] = *(const bf16x8*)&Psw[(mg * 16 + l16) * 72 + quad * 8];
            a_p[mg][1] = *(const bf16x8*)&Psw[(mg * 16 + l16) * 72 + 32 + quad * 8];
        }

        #pragma unroll
        for (int nt = 0; nt < 4; nt++) {
            int d = nt * 16 + l16;
            bf16x8 bv0 = *(const bf16x8*)&VsH[d * 64 + ((quad ^ (d & 7)) << 3)];
            bf16x8 bv1 = *(const bf16x8*)&VsH[d * 64 + (((4 + quad) ^ (d & 7)) << 3)];
            #pragma unroll
            for (int mg = 0; mg < 2; mg++) {
                o[mg][nt] = __builtin_amdgcn_mfma_f32_16x16x32_bf16(a_p[mg][0], bv0, o[mg][nt], 0, 0, 0);
                o[mg][nt] = __builtin_amdgcn_mfma_f32_16x16x32_bf16(a_p[mg][1], bv1, o[mg][nt], 0, 0, 0);
            }
        }
        #pragma unroll
        for (int mg = 0; mg < 2; mg++) {
            lacc[mg] = __builtin_amdgcn_mfma_f32_16x16x32_bf16(a_p[mg][0], b_ones, lacc[mg], 0, 0, 0);
            lacc[mg] = __builtin_amdgcn_mfma_f32_16x16x32_bf16(a_p[mg][1], b_ones, lacc[mg], 0, 0, 0);
        }
    }

    __syncthreads();
    float* osc = (float*)smem;
    float* lsc = (float*)(smem + 16384);
    const int fo = wavel * 2048 + quad * 64 + l16 * 4;
    const int fl = wavel * 512 + quad * 64 + l16 * 4;
    if (kh == 1) {
        #pragma unroll
        for (int mg = 0; mg < 2; mg++) {
            #pragma unroll
            for (int nt = 0; nt < 4; nt++)
                *(f32x4*)&osc[fo + (mg * 4 + nt) * 256] = o[mg][nt];
            *(f32x4*)&lsc[fl + mg * 256] = lacc[mg];
        }
    }
    __syncthreads();
    if (kh == 0) {
        #pragma unroll
        for (int mg = 0; mg < 2; mg++) {
            #pragma unroll
            for (int nt = 0; nt < 4; nt++)
                o[mg][nt] += *(const f32x4*)&osc[fo + (mg * 4 + nt) * 256];
            lacc[mg] += *(const f32x4*)&lsc[fl + mg * 256];
        }
        #pragma unroll
        for (int mg = 0; mg < 2; mg++) {
            #pragma unroll
            for (int r = 0; r < 4; r++) {
                float inv = 1.f / lacc[mg][r];
                int row = b * SEQ + qbase + wavel * 32 + mg * 16 + quad * 4 + r;
                size_t base = (size_t)row * HIDDEN + hoff + l16;
                #pragma unroll
                for (int nt = 0; nt < 4; nt++)
                    attn[base + nt * 16] = f2bf(o[mg][nt][r] * inv);
            }
        }
    }
}

extern "C" void kernel_launch(void* const* d_in, const int* in_sizes, int n_in,
                              void* d_out, int out_size, void* d_ws, size_t ws_size,
                              hipStream_t stream) {
    const float* x    = (const float*)d_in[0];
    const float* Wqkv = (const float*)d_in[1];
    const float* bqkv = (const float*)d_in[2];
    const float* Wo   = (const float*)d_in[3];
    const float* bo   = (const float*)d_in[4];
    float* out = (float*)d_out;

    const int M = BATCH * SEQ;                   // 4096
    const size_t MB = 1024 * 1024;

    // workspace (48 MB):
    //   [0,24) qkvb | [24,32) attn (xb overlaps: prep/GEMM1 only)
    //   [32,38) Wt (prep/GEMM1) | [38,40) WoT (prep->GEMM3) | [40,48) vtg
    char* ws = (char*)d_ws;
    ushort* qkvb = (ushort*)ws;
    ushort* attn = (ushort*)(ws + 24 * MB);
    ushort* xb   = (ushort*)(ws + 24 * MB);
    ushort* Wt   = (ushort*)(ws + 32 * MB);
    ushort* WoT  = (ushort*)(ws + 38 * MB);
    ushort* vtg  = (ushort*)(ws + 40 * MB);
    const int use_vtg = (ws_size >= 48 * MB) ? 1 : 0;

    const float qscale = 0.125f * 1.44269504088896f;   // fold log2e -> exp2 softmax

    // 0) fused preps (x->bf16, Wqkv transpose, Wo transpose)
    prep_kernel<<<8192, 256, 0, stream>>>(x, Wqkv, Wo, xb, Wt, WoT);

    // 1) qkv = (x @ Wqkv + bqkv) -> bf16; V written transposed to vtg when able
    {
        dim3 grid((3 * HIDDEN) / 128, M / 128);
        gemm_mfma_bf16_kernel<<<grid, 256, 0, stream>>>(xb, Wt, bqkv, qkvb,
                                                        3 * HIDDEN, HIDDEN, qscale,
                                                        vtg, use_vtg);
    }

    // 2) flash attention -> attn bf16.
    // MEASUREMENT ROUND: PH=1..3 are diagnostic dispatches (garbage output,
    // scratch region only, overwritten by PH=4 which runs LAST and is the
    // real kernel). dur_us regresses this round by design; rocprof rows for
    // each instantiation give the phase-marginal attribution.
    if (use_vtg) {
        const int grid = BATCH * NH * (SEQ / 128);
        attn_ab_kernel<1><<<grid, 256, 0, stream>>>(qkvb, vtg, attn);
        attn_ab_kernel<2><<<grid, 256, 0, stream>>>(qkvb, vtg, attn);
        attn_ab_kernel<3><<<grid, 256, 0, stream>>>(qkvb, vtg, attn);
        attn_ab_kernel<4><<<grid, 256, 0, stream>>>(qkvb, vtg, attn);  // real
    } else {
        attn_mfma_fb_kernel<<<BATCH * NH * (SEQ / 128), 512, 0, stream>>>(
            qkvb, attn);
    }

    // 3) out = attn @ Wo + bo (single-pass bf16 MFMA)
    {
        dim3 grid(HIDDEN / 64, M / 128);
        gemm_out_kernel<<<grid, 256, 0, stream>>>(attn, WoT, bo, out);
    }
}

// Round 8
// 174.896 us; speedup vs baseline: 1.4303x; 1.4303x over previous
//
#include <hip/hip_runtime.h>
#include <hip/hip_bf16.h>

#define HIDDEN 1024
#define NH 16
#define BATCH 2
#define SEQ 2048

typedef __attribute__((ext_vector_type(8))) short bf16x8;
typedef __attribute__((ext_vector_type(4))) float f32x4;
typedef __attribute__((ext_vector_type(2))) uint uint2v;

__device__ __forceinline__ ushort f2bf(float f) {
    __hip_bfloat16 h = __float2bfloat16(f);
    return *reinterpret_cast<ushort*>(&h);
}
__device__ __forceinline__ float fexp2(float x) {
#if __has_builtin(__builtin_amdgcn_exp2f)
    return __builtin_amdgcn_exp2f(x);
#else
    return exp2f(x);
#endif
}
// pack trunc-bf16(a) low, trunc-bf16(b) high (1 v_perm)
__device__ __forceinline__ uint pack_bf_trunc(float a, float b) {
    return __builtin_amdgcn_perm(__float_as_uint(b), __float_as_uint(a), 0x07060302u);
}

// butterfly: (A,B) -> A' = [a0,b0,a1,b1], B' = [a2,b2,a3,b3] (16-lane rows).
__device__ __forceinline__ void bfly(uint &a, uint &b) {
#if __has_builtin(__builtin_amdgcn_permlane16_swap)
    uint2v t = __builtin_amdgcn_permlane16_swap(a, b, false, false);
    uint2v s = __builtin_amdgcn_permlane32_swap(t[0], t[1], false, false);
    a = s[0]; b = s[1];
#else
    asm volatile("v_permlane16_swap_b32 %0, %1" : "+v"(a), "+v"(b));
    asm volatile("v_permlane32_swap_b32 %0, %1" : "+v"(a), "+v"(b));
#endif
}

// async global->LDS, 16B per lane
__device__ __forceinline__ void async_copy16(const ushort* g, ushort* l) {
    __builtin_amdgcn_global_load_lds((const __attribute__((address_space(1))) void*)g,
                                     (__attribute__((address_space(3))) void*)l,
                                     16, 0, 0);
}

// ---------------------------------------------------------------------------
// Fused prep: [0,4096) x->bf16 | [4096,7168) Wqkv transpose | [7168,8192) Wo transpose
// ---------------------------------------------------------------------------
__global__ void prep_kernel(const float* __restrict__ x,
                            const float* __restrict__ Wqkv,
                            const float* __restrict__ Wo,
                            ushort* __restrict__ xb,
                            ushort* __restrict__ Wt,
                            ushort* __restrict__ WoT)
{
    __shared__ float t[32][33];
    const int bid = blockIdx.x;
    const int tid = threadIdx.x;

    if (bid < 4096) {
        int i = (bid * 256 + tid) * 4;
        float4 v = *(const float4*)(x + i);
        ushort4 w;
        w.x = f2bf(v.x); w.y = f2bf(v.y); w.z = f2bf(v.z); w.w = f2bf(v.w);
        *(ushort4*)(xb + i) = w;
        return;
    }
    const int r = tid >> 3;
    const int c = (tid & 7) * 4;
    if (bid < 7168) {
        int tt = bid - 4096;
        int k0 = (tt & 31) * 32;
        int n0 = (tt >> 5) * 32;
        const int N = 3 * HIDDEN, K = HIDDEN;
        float4 v = *(const float4*)(Wqkv + (size_t)(k0 + r) * N + n0 + c);
        t[r][c] = v.x; t[r][c + 1] = v.y; t[r][c + 2] = v.z; t[r][c + 3] = v.w;
        __syncthreads();
        ushort4 w;
        w.x = f2bf(t[c + 0][r]); w.y = f2bf(t[c + 1][r]);
        w.z = f2bf(t[c + 2][r]); w.w = f2bf(t[c + 3][r]);
        *(ushort4*)(Wt + (size_t)(n0 + r) * K + k0 + c) = w;
    } else {
        int tt = bid - 7168;
        int k0 = (tt & 31) * 32;
        int n0 = (tt >> 5) * 32;
        const int N = HIDDEN, K = HIDDEN;
        float4 v = *(const float4*)(Wo + (size_t)(k0 + r) * N + n0 + c);
        t[r][c] = v.x; t[r][c + 1] = v.y; t[r][c + 2] = v.z; t[r][c + 3] = v.w;
        __syncthreads();
        ushort4 w;
        w.x = f2bf(t[c + 0][r]); w.y = f2bf(t[c + 1][r]);
        w.z = f2bf(t[c + 2][r]); w.w = f2bf(t[c + 3][r]);
        *(ushort4*)(WoT + (size_t)(n0 + r) * K + k0 + c) = w;
    }
}

// ---------------------------------------------------------------------------
// bf16 MFMA GEMM1: qkv = x @ Wqkv^T + bias -> bf16. Q cols scaled by qscale
// (0.125*log2e -> softmax via exp2). When vt_mode, V cols (>=2048) go
// transposed + Pi-permuted into vtg[b][h][d][s'] (fused transpose_v).
// ---------------------------------------------------------------------------
__global__ __launch_bounds__(256, 3)
void gemm_mfma_bf16_kernel(const ushort* __restrict__ A,
                           const ushort* __restrict__ Bt,
                           const float* __restrict__ bias,
                           ushort* __restrict__ C, int N,
                           int qscale_cols, float qscale,
                           ushort* __restrict__ vtg, int vt_mode)
{
    constexpr int K = 1024;
    __shared__ ushort As[128 * 64];
    __shared__ ushort Bs[128 * 64];

    const int tid  = threadIdx.x;
    const int wave = tid >> 6;
    const int lane = tid & 63;
    const int l16  = lane & 15;
    const int quad = lane >> 4;
    const int wm = wave & 1, wn = wave >> 1;

    const int bm = blockIdx.y * 128;
    const int bn = blockIdx.x * 128;

    const int srow = lane >> 3;
    const int lblk = (lane & 7) ^ srow;
    const ushort* Ag = A  + (size_t)(bm + wave * 32 + srow) * K + lblk * 8;
    const ushort* Bg = Bt + (size_t)(bn + wave * 32 + srow) * K + lblk * 8;
    ushort* Asl = As + wave * 32 * 64;
    ushort* Bsl = Bs + wave * 32 * 64;

    f32x4 acc[4][4];
    #pragma unroll
    for (int i = 0; i < 4; i++)
        #pragma unroll
        for (int j = 0; j < 4; j++) acc[i][j] = (f32x4){0.f, 0.f, 0.f, 0.f};

    for (int k0 = 0; k0 < K; k0 += 64) {
        __syncthreads();
        #pragma unroll
        for (int t = 0; t < 4; t++) {
            async_copy16(Ag + (size_t)t * 8 * K + k0, Asl + t * 8 * 64);
            async_copy16(Bg + (size_t)t * 8 * K + k0, Bsl + t * 8 * 64);
        }
        __syncthreads();

        #pragma unroll
        for (int s = 0; s < 2; s++) {
            bf16x8 af[4], bfr[4];
            #pragma unroll
            for (int i = 0; i < 4; i++) {
                int m = wm * 64 + i * 16 + l16;
                int n = wn * 64 + i * 16 + l16;
                af[i]  = *(const bf16x8*)&As[m * 64 + (((s * 4 + quad) ^ (m & 7)) << 3)];
                bfr[i] = *(const bf16x8*)&Bs[n * 64 + (((s * 4 + quad) ^ (n & 7)) << 3)];
            }
            #pragma unroll
            for (int i = 0; i < 4; i++)
                #pragma unroll
                for (int j = 0; j < 4; j++)
                    acc[i][j] = __builtin_amdgcn_mfma_f32_16x16x32_bf16(af[i], bfr[j], acc[i][j], 0, 0, 0);
        }
    }

    #pragma unroll
    for (int j = 0; j < 4; j++) {
        int col = bn + wn * 64 + j * 16 + l16;
        float bv = bias[col];
        if (vt_mode && col >= 2048) {
            // V -> vtg transposed + Pi: s64 = i*16+quad*4+r; Pi(s64)=(quad*4+r)*4+i
            int dfull = col - 2048;
            int hh = dfull >> 6, dd = dfull & 63;
            int bb = bm >> 11;
            int sb = ((bm & 2047) + wm * 64) >> 6;
            ushort tmp[16];
            #pragma unroll
            for (int i = 0; i < 4; i++)
                #pragma unroll
                for (int r = 0; r < 4; r++)
                    tmp[r * 4 + i] = f2bf(acc[i][j][r] + bv);
            ushort* dst = vtg + ((size_t)((bb * NH + hh) * 64 + dd)) * SEQ
                          + sb * 64 + quad * 16;
            *(uint4*)dst = *(const uint4*)tmp;
            *(uint4*)(dst + 8) = *(const uint4*)(tmp + 8);
        } else {
            float s = (col < qscale_cols) ? qscale : 1.0f;
            #pragma unroll
            for (int i = 0; i < 4; i++) {
                int row0 = bm + wm * 64 + i * 16 + quad * 4;
                #pragma unroll
                for (int r = 0; r < 4; r++)
                    C[(size_t)(row0 + r) * N + col] = f2bf((acc[i][j][r] + bv) * s);
            }
        }
    }
}

// ---------------------------------------------------------------------------
// Output projection, single-pass bf16 MFMA: C[4096][1024]f32 = attn @ WoT^T + bo.
// ---------------------------------------------------------------------------
__global__ __launch_bounds__(256, 4)
void gemm_out_kernel(const ushort* __restrict__ A,
                     const ushort* __restrict__ Bt,
                     const float* __restrict__ bias,
                     float* __restrict__ C)
{
    constexpr int K = 1024, N = 1024;
    __shared__ ushort As[128 * 64];
    __shared__ ushort Bs[64 * 64];

    const int tid  = threadIdx.x;
    const int wave = tid >> 6;
    const int lane = tid & 63;
    const int l16  = lane & 15;
    const int quad = lane >> 4;
    const int wm = wave & 1, wn = wave >> 1;

    const int bm = blockIdx.y * 128;
    const int bn = blockIdx.x * 64;

    const int srow = lane >> 3;
    const int lblk = (lane & 7) ^ srow;
    const ushort* Ag = A  + (size_t)(bm + wave * 32 + srow) * K + lblk * 8;
    const ushort* Bg = Bt + (size_t)(bn + wave * 16 + srow) * K + lblk * 8;
    ushort* Asl = As + wave * 32 * 64;
    ushort* Bsl = Bs + wave * 16 * 64;

    f32x4 acc[4][2];
    #pragma unroll
    for (int i = 0; i < 4; i++)
        #pragma unroll
        for (int j = 0; j < 2; j++) acc[i][j] = (f32x4){0.f, 0.f, 0.f, 0.f};

    for (int k0 = 0; k0 < K; k0 += 64) {
        __syncthreads();
        #pragma unroll
        for (int t = 0; t < 4; t++)
            async_copy16(Ag + (size_t)t * 8 * K + k0, Asl + t * 8 * 64);
        #pragma unroll
        for (int t = 0; t < 2; t++)
            async_copy16(Bg + (size_t)t * 8 * K + k0, Bsl + t * 8 * 64);
        __syncthreads();

        #pragma unroll
        for (int s = 0; s < 2; s++) {
            bf16x8 af[4], bfr[2];
            #pragma unroll
            for (int i = 0; i < 4; i++) {
                int m = wm * 64 + i * 16 + l16;
                af[i] = *(const bf16x8*)&As[m * 64 + (((s * 4 + quad) ^ (m & 7)) << 3)];
            }
            #pragma unroll
            for (int j = 0; j < 2; j++) {
                int n = wn * 32 + j * 16 + l16;
                bfr[j] = *(const bf16x8*)&Bs[n * 64 + (((s * 4 + quad) ^ (n & 7)) << 3)];
            }
            #pragma unroll
            for (int i = 0; i < 4; i++)
                #pragma unroll
                for (int j = 0; j < 2; j++)
                    acc[i][j] = __builtin_amdgcn_mfma_f32_16x16x32_bf16(af[i], bfr[j], acc[i][j], 0, 0, 0);
        }
    }

    #pragma unroll
    for (int j = 0; j < 2; j++) {
        int col = bn + wn * 32 + j * 16 + l16;
        float bv = bias[col];
        #pragma unroll
        for (int i = 0; i < 4; i++) {
            int row0 = bm + wm * 64 + i * 16 + quad * 4;
            #pragma unroll
            for (int r = 0; r < 4; r++)
                C[(size_t)(row0 + r) * N + col] = acc[i][j][r] + bv;
        }
    }
}

// ---------------------------------------------------------------------------
// v13 64-key sub-body: identical math to v12's verified iteration body.
// Swapped QK^T (P lane-local), exp2+pack+butterfly in-register, PV + l.
// ---------------------------------------------------------------------------
__device__ __forceinline__ void attn_tile64(
    const ushort* Ks, const ushort* Vs,
    const bf16x8 (&a_q)[2][2], f32x4 (&o)[2][4], f32x4 (&lacc)[2],
    const bf16x8 &b_ones, int l16, int quad)
{
    // swapped QK^T: D[row=key-in-tile=quad*4+r][col=q=l16].
    f32x4 sc[2][4];
    __builtin_amdgcn_s_setprio(1);
    #pragma unroll
    for (int nt = 0; nt < 4; nt++) {
        int key = nt * 16 + l16;
        bf16x8 bk0 = *(const bf16x8*)&Ks[key * 64 + ((quad ^ (key & 7)) << 3)];
        bf16x8 bk1 = *(const bf16x8*)&Ks[key * 64 + (((4 + quad) ^ (key & 7)) << 3)];
        #pragma unroll
        for (int mg = 0; mg < 2; mg++) {
            f32x4 a = (f32x4){0.f, 0.f, 0.f, 0.f};
            a = __builtin_amdgcn_mfma_f32_16x16x32_bf16(bk0, a_q[mg][0], a, 0, 0, 0);
            a = __builtin_amdgcn_mfma_f32_16x16x32_bf16(bk1, a_q[mg][1], a, 0, 0, 0);
            sc[mg][nt] = a;
        }
    }
    __builtin_amdgcn_s_setprio(0);

    // exp2 + pack (nt0 with nt1, nt2 with nt3) + butterfly -> PV frags.
    bf16x8 ap[2][2];
    #pragma unroll
    for (int mg = 0; mg < 2; mg++) {
        uint w00 = pack_bf_trunc(fexp2(sc[mg][0][0]), fexp2(sc[mg][1][0]));
        uint w01 = pack_bf_trunc(fexp2(sc[mg][0][1]), fexp2(sc[mg][1][1]));
        uint w02 = pack_bf_trunc(fexp2(sc[mg][0][2]), fexp2(sc[mg][1][2]));
        uint w03 = pack_bf_trunc(fexp2(sc[mg][0][3]), fexp2(sc[mg][1][3]));
        uint w10 = pack_bf_trunc(fexp2(sc[mg][2][0]), fexp2(sc[mg][3][0]));
        uint w11 = pack_bf_trunc(fexp2(sc[mg][2][1]), fexp2(sc[mg][3][1]));
        uint w12 = pack_bf_trunc(fexp2(sc[mg][2][2]), fexp2(sc[mg][3][2]));
        uint w13 = pack_bf_trunc(fexp2(sc[mg][2][3]), fexp2(sc[mg][3][3]));
        bfly(w00, w02);
        bfly(w01, w03);
        bfly(w10, w12);
        bfly(w11, w13);
        union { uint u[4]; bf16x8 h; } u0, u1;
        u0.u[0] = w00; u0.u[1] = w10; u0.u[2] = w01; u0.u[3] = w11;
        u1.u[0] = w02; u1.u[1] = w12; u1.u[2] = w03; u1.u[3] = w13;
        ap[mg][0] = u0.h;
        ap[mg][1] = u1.h;
    }

    // PV + l via ones-MFMA; V fragment loaded once, used by both mg
    __builtin_amdgcn_s_setprio(1);
    #pragma unroll
    for (int nt = 0; nt < 4; nt++) {
        int d = nt * 16 + l16;
        bf16x8 bv0 = *(const bf16x8*)&Vs[d * 64 + ((quad ^ (d & 7)) << 3)];
        bf16x8 bv1 = *(const bf16x8*)&Vs[d * 64 + (((4 + quad) ^ (d & 7)) << 3)];
        #pragma unroll
        for (int mg = 0; mg < 2; mg++) {
            o[mg][nt] = __builtin_amdgcn_mfma_f32_16x16x32_bf16(ap[mg][0], bv0, o[mg][nt], 0, 0, 0);
            o[mg][nt] = __builtin_amdgcn_mfma_f32_16x16x32_bf16(ap[mg][1], bv1, o[mg][nt], 0, 0, 0);
        }
    }
    #pragma unroll
    for (int mg = 0; mg < 2; mg++) {
        lacc[mg] = __builtin_amdgcn_mfma_f32_16x16x32_bf16(ap[mg][0], b_ones, lacc[mg], 0, 0, 0);
        lacc[mg] = __builtin_amdgcn_mfma_f32_16x16x32_bf16(ap[mg][1], b_ones, lacc[mg], 0, 0, 0);
    }
    __builtin_amdgcn_s_setprio(0);
}

// ---------------------------------------------------------------------------
// Flash attention v13: KVBLK=128 (two v12 sub-bodies per barrier).
// Round-7 ablation: t1(stage+sync skeleton) ~10-20us of 46, marginals
// near-additive -> per-iteration fixed costs (barrier jitter + vmcnt drain)
// x32 iters are first-order. v13 halves iterations: 16 x 128-key tiles,
// ONE barrier per tile, K staged at iter top / V staged between sub-bodies
// (spreads VM queue; both drain at the single barrier under ~2 bodies of
// compute). LDS 64 KB (2buf x [K 16KB + V 16KB]), still 2 blocks/CU.
// Sub-bodies bit-identical to v12's verified body -> absmax unchanged.
// ---------------------------------------------------------------------------
__global__ __launch_bounds__(256, 2)
void attn_mfma_v13_kernel(const ushort* __restrict__ qkvb,
                          const ushort* __restrict__ vtg,
                          ushort* __restrict__ attn)
{
    // ushort layout: K[2][8192] @0 | V[2][8192] @16384  -> 64 KB
    // each 8192-ushort buffer = two 64x64 sub-tiles (4096 each)
    __shared__ __align__(16) ushort smem[32768];

    const int tid  = threadIdx.x;
    const int wave = tid >> 6;
    const int lane = tid & 63;
    const int l16  = lane & 15;
    const int quad = lane >> 4;

    // XCD swizzle: xcd = bid&7 gets heads [xcd*4, xcd*4+4), all 16 qb each.
    const int obid = blockIdx.x;
    const int qb = (obid >> 3) & 15;
    const int bh = (obid & 7) * 4 + (obid >> 7);
    const int h  = bh & (NH - 1);
    const int b  = bh >> 4;

    const int qbase = qb * 128 + wave * 32;   // 32 q-rows per wave
    const int hoff  = h * 64;

    // Q fragments: 2 row-groups of 16 (used as the MFMA *B* operand)
    bf16x8 a_q[2][2];
    #pragma unroll
    for (int mg = 0; mg < 2; mg++) {
        int qrow = b * SEQ + qbase + mg * 16 + l16;
        const ushort* qp = qkvb + (size_t)qrow * 3072 + hoff + quad * 8;
        a_q[mg][0] = *(const bf16x8*)qp;
        a_q[mg][1] = *(const bf16x8*)(qp + 32);
    }

    f32x4 o[2][4];
    f32x4 lacc[2];
    #pragma unroll
    for (int mg = 0; mg < 2; mg++) {
        lacc[mg] = (f32x4){0.f, 0.f, 0.f, 0.f};
        #pragma unroll
        for (int nt = 0; nt < 4; nt++) o[mg][nt] = (f32x4){0.f, 0.f, 0.f, 0.f};
    }

    bf16x8 b_ones;
    #pragma unroll
    for (int j = 0; j < 8; j++) b_ones[j] = (short)0x3f80;

    const ushort* kvb    = qkvb + (size_t)b * SEQ * 3072;
    const ushort* vtg_bh = vtg + (size_t)((b * NH + h) * 64) * SEQ;

    // staging: per 128-key tile, 8 calls/thread (4 K + 4 V), 32 KB total.
    // global col pre-swizzled so linear LDS dest yields XOR-swizzled layout.
    const int srow8 = lane >> 3;
    const int gblk  = ((lane & 7) ^ srow8) << 3;
    const ushort* kg = kvb + (size_t)(wave * 16 + srow8) * 3072 + 1024 + hoff + gblk;
    const ushort* vg = vtg_bh + (size_t)(wave * 16 + srow8) * SEQ + gblk;

    ushort* k_dst = smem + wave * 1024;          // + s*4096 + c*512 + cur*8192
    ushort* v_dst = smem + 16384 + wave * 1024;  // + s*4096 + c*512 + cur*8192

    // prologue: stage tile 0 (keys 0..127) into buf 0; barrier drains vmcnt
    #pragma unroll
    for (int s = 0; s < 2; s++)
        #pragma unroll
        for (int c = 0; c < 2; c++) {
            async_copy16(kg + (size_t)(s * 64 + c * 8) * 3072,
                         k_dst + s * 4096 + c * 512);
            async_copy16(vg + (size_t)(c * 8) * SEQ + s * 64,
                         v_dst + s * 4096 + c * 512);
        }
    __syncthreads();

    int cur = 0;
    for (int t = 0; t < 16; t++) {
        const int nb = (cur ^ 1) << 13;   // next buffer offset (8192 ushorts)
        // issue next tile's K loads (drained at end-of-iter barrier,
        // ~2 sub-bodies of compute to hide under)
        if (t < 15) {
            const int k0n = (t + 1) * 128;
            #pragma unroll
            for (int s = 0; s < 2; s++)
                #pragma unroll
                for (int c = 0; c < 2; c++)
                    async_copy16(kg + (size_t)(k0n + s * 64 + c * 8) * 3072,
                                 k_dst + nb + s * 4096 + c * 512);
        }

        const ushort* Kc = smem + (cur << 13);
        const ushort* Vc = smem + 16384 + (cur << 13);

        // sub-body 0: keys t*128 .. +63
        attn_tile64(Kc, Vc, a_q, o, lacc, b_ones, l16, quad);

        // issue next tile's V loads between sub-bodies (~1 body of cover)
        if (t < 15) {
            const int k0n = (t + 1) * 128;
            #pragma unroll
            for (int s = 0; s < 2; s++)
                #pragma unroll
                for (int c = 0; c < 2; c++)
                    async_copy16(vg + (size_t)(c * 8) * SEQ + k0n + s * 64,
                                 v_dst + nb + s * 4096 + c * 512);
        }

        // sub-body 1: keys t*128+64 .. +127
        attn_tile64(Kc + 4096, Vc + 4096, a_q, o, lacc, b_ones, l16, quad);

        // single barrier per 128 keys: everyone done reading buf[cur],
        // next tile's 8 staged loads drained here.
        __syncthreads();
        cur ^= 1;
    }

    // epilogue: per-wave, no cross-wave combine
    #pragma unroll
    for (int mg = 0; mg < 2; mg++) {
        #pragma unroll
        for (int r = 0; r < 4; r++) {
            float inv = 1.f / lacc[mg][r];
            int row = b * SEQ + qbase + mg * 16 + quad * 4 + r;
            size_t base = (size_t)row * HIDDEN + hoff + l16;
            #pragma unroll
            for (int nt = 0; nt < 4; nt++)
                attn[base + nt * 16] = f2bf(o[mg][nt][r] * inv);
        }
    }
}

// ---------------------------------------------------------------------------
// Fallback attention (no vtg workspace): barrier kernel staging K + Pi-V.
// ---------------------------------------------------------------------------
__global__ __launch_bounds__(512, 4)
void attn_mfma_fb_kernel(const ushort* __restrict__ qkvb,
                         ushort* __restrict__ attn)
{
    __shared__ __align__(16) ushort smem[34816];

    const int tid   = threadIdx.x;
    const int wave  = tid >> 6;
    const int wavel = wave & 3;
    const int kh    = wave >> 2;
    const int lane  = tid & 63;
    const int l16   = lane & 15;
    const int quad  = lane >> 4;

    const int qb = blockIdx.x & 15;
    const int bh = blockIdx.x >> 4;
    const int h  = bh & (NH - 1);
    const int b  = bh >> 4;

    const int qbase = qb * 128;
    const int hoff  = h * 64;

    ushort* KsH = smem + kh * 4096;
    ushort* VsH = smem + 8192 + kh * 4096;
    ushort* Psw = smem + 16384 + wave * 2304;

    bf16x8 a_q[2][2];
    #pragma unroll
    for (int mg = 0; mg < 2; mg++) {
        int qrow = b * SEQ + qbase + wavel * 32 + mg * 16 + l16;
        const ushort* qp = qkvb + (size_t)qrow * 3072 + hoff + quad * 8;
        a_q[mg][0] = *(const bf16x8*)qp;
        a_q[mg][1] = *(const bf16x8*)(qp + 32);
    }

    f32x4 o[2][4];
    f32x4 lacc[2];
    #pragma unroll
    for (int mg = 0; mg < 2; mg++) {
        lacc[mg] = (f32x4){0.f, 0.f, 0.f, 0.f};
        #pragma unroll
        for (int nt = 0; nt < 4; nt++) o[mg][nt] = (f32x4){0.f, 0.f, 0.f, 0.f};
    }

    bf16x8 b_ones;
    #pragma unroll
    for (int j = 0; j < 8; j++) b_ones[j] = (short)0x3f80;

    const ushort* kvb = qkvb + (size_t)b * SEQ * 3072;

    for (int t = 0; t < 16; t++) {
        const int k0 = t * 64;
        __syncthreads();
        {
            const int tl = tid & 255;
            #pragma unroll
            for (int i = 0; i < 2; i++) {
                int key = (tl >> 3) + 32 * i;
                int blk = tl & 7;
                const ushort* ksrc = kvb + (size_t)(kh * 1024 + k0 + key) * 3072 + 1024 + hoff + blk * 8;
                uint4 kv = *(const uint4*)ksrc;
                *(uint4*)&KsH[key * 64 + ((blk ^ (key & 7)) << 3)] = kv;
                uint4 vv = *(const uint4*)(ksrc + 1024);
                const ushort* vpp = (const ushort*)&vv;
                int pk_ = (key & 15) * 4 + (key >> 4);
                #pragma unroll
                for (int j = 0; j < 8; j++) {
                    int d = blk * 8 + j;
                    VsH[d * 64 + (((pk_ >> 3) ^ (d & 7)) << 3) + (pk_ & 7)] = vpp[j];
                }
            }
        }
        __syncthreads();

        f32x4 sc[2][4];
        #pragma unroll
        for (int nt = 0; nt < 4; nt++) {
            int key = nt * 16 + l16;
            bf16x8 bk0 = *(const bf16x8*)&KsH[key * 64 + ((quad ^ (key & 7)) << 3)];
            bf16x8 bk1 = *(const bf16x8*)&KsH[key * 64 + (((4 + quad) ^ (key & 7)) << 3)];
            #pragma unroll
            for (int mg = 0; mg < 2; mg++) {
                f32x4 a = (f32x4){0.f, 0.f, 0.f, 0.f};
                a = __builtin_amdgcn_mfma_f32_16x16x32_bf16(a_q[mg][0], bk0, a, 0, 0, 0);
                a = __builtin_amdgcn_mfma_f32_16x16x32_bf16(a_q[mg][1], bk1, a, 0, 0, 0);
                sc[mg][nt] = a;
            }
        }

        #pragma unroll
        for (int mg = 0; mg < 2; mg++) {
            #pragma unroll
            for (int r = 0; r < 4; r++) {
                int q = mg * 16 + quad * 4 + r;
                uint2 pk2;
                pk2.x = pack_bf_trunc(fexp2(sc[mg][0][r]), fexp2(sc[mg][1][r]));
                pk2.y = pack_bf_trunc(fexp2(sc[mg][2][r]), fexp2(sc[mg][3][r]));
                *(uint2*)&Psw[q * 72 + l16 * 4] = pk2;
            }
        }

        asm volatile("s_waitcnt lgkmcnt(0)" ::: "memory");
        bf16x8 a_p[2][2];
        #pragma unroll
        for (int mg = 0; mg < 2; mg++) {
            a_p[mg][0] = *(const bf16x8*)&Psw[(mg * 16 + l16) * 72 + quad * 8];
            a_p[mg][1] = *(const bf16x8*)&Psw[(mg * 16 + l16) * 72 + 32 + quad * 8];
        }

        #pragma unroll
        for (int nt = 0; nt < 4; nt++) {
            int d = nt * 16 + l16;
            bf16x8 bv0 = *(const bf16x8*)&VsH[d * 64 + ((quad ^ (d & 7)) << 3)];
            bf16x8 bv1 = *(const bf16x8*)&VsH[d * 64 + (((4 + quad) ^ (d & 7)) << 3)];
            #pragma unroll
            for (int mg = 0; mg < 2; mg++) {
                o[mg][nt] = __builtin_amdgcn_mfma_f32_16x16x32_bf16(a_p[mg][0], bv0, o[mg][nt], 0, 0, 0);
                o[mg][nt] = __builtin_amdgcn_mfma_f32_16x16x32_bf16(a_p[mg][1], bv1, o[mg][nt], 0, 0, 0);
            }
        }
        #pragma unroll
        for (int mg = 0; mg < 2; mg++) {
            lacc[mg] = __builtin_amdgcn_mfma_f32_16x16x32_bf16(a_p[mg][0], b_ones, lacc[mg], 0, 0, 0);
            lacc[mg] = __builtin_amdgcn_mfma_f32_16x16x32_bf16(a_p[mg][1], b_ones, lacc[mg], 0, 0, 0);
        }
    }

    __syncthreads();
    float* osc = (float*)smem;
    float* lsc = (float*)(smem + 16384);
    const int fo = wavel * 2048 + quad * 64 + l16 * 4;
    const int fl = wavel * 512 + quad * 64 + l16 * 4;
    if (kh == 1) {
        #pragma unroll
        for (int mg = 0; mg < 2; mg++) {
            #pragma unroll
            for (int nt = 0; nt < 4; nt++)
                *(f32x4*)&osc[fo + (mg * 4 + nt) * 256] = o[mg][nt];
            *(f32x4*)&lsc[fl + mg * 256] = lacc[mg];
        }
    }
    __syncthreads();
    if (kh == 0) {
        #pragma unroll
        for (int mg = 0; mg < 2; mg++) {
            #pragma unroll
            for (int nt = 0; nt < 4; nt++)
                o[mg][nt] += *(const f32x4*)&osc[fo + (mg * 4 + nt) * 256];
            lacc[mg] += *(const f32x4*)&lsc[fl + mg * 256];
        }
        #pragma unroll
        for (int mg = 0; mg < 2; mg++) {
            #pragma unroll
            for (int r = 0; r < 4; r++) {
                float inv = 1.f / lacc[mg][r];
                int row = b * SEQ + qbase + wavel * 32 + mg * 16 + quad * 4 + r;
                size_t base = (size_t)row * HIDDEN + hoff + l16;
                #pragma unroll
                for (int nt = 0; nt < 4; nt++)
                    attn[base + nt * 16] = f2bf(o[mg][nt][r] * inv);
            }
        }
    }
}

extern "C" void kernel_launch(void* const* d_in, const int* in_sizes, int n_in,
                              void* d_out, int out_size, void* d_ws, size_t ws_size,
                              hipStream_t stream) {
    const float* x    = (const float*)d_in[0];
    const float* Wqkv = (const float*)d_in[1];
    const float* bqkv = (const float*)d_in[2];
    const float* Wo   = (const float*)d_in[3];
    const float* bo   = (const float*)d_in[4];
    float* out = (float*)d_out;

    const int M = BATCH * SEQ;                   // 4096
    const size_t MB = 1024 * 1024;

    // workspace (48 MB):
    //   [0,24) qkvb | [24,32) attn (xb overlaps: prep/GEMM1 only)
    //   [32,38) Wt (prep/GEMM1) | [38,40) WoT (prep->GEMM3) | [40,48) vtg
    char* ws = (char*)d_ws;
    ushort* qkvb = (ushort*)ws;
    ushort* attn = (ushort*)(ws + 24 * MB);
    ushort* xb   = (ushort*)(ws + 24 * MB);
    ushort* Wt   = (ushort*)(ws + 32 * MB);
    ushort* WoT  = (ushort*)(ws + 38 * MB);
    ushort* vtg  = (ushort*)(ws + 40 * MB);
    const int use_vtg = (ws_size >= 48 * MB) ? 1 : 0;

    const float qscale = 0.125f * 1.44269504088896f;   // fold log2e -> exp2 softmax

    // 0) fused preps (x->bf16, Wqkv transpose, Wo transpose)
    prep_kernel<<<8192, 256, 0, stream>>>(x, Wqkv, Wo, xb, Wt, WoT);

    // 1) qkv = (x @ Wqkv + bqkv) -> bf16; V written transposed to vtg when able
    {
        dim3 grid((3 * HIDDEN) / 128, M / 128);
        gemm_mfma_bf16_kernel<<<grid, 256, 0, stream>>>(xb, Wt, bqkv, qkvb,
                                                        3 * HIDDEN, HIDDEN, qscale,
                                                        vtg, use_vtg);
    }

    // 2) flash attention -> attn bf16
    if (use_vtg) {
        attn_mfma_v13_kernel<<<BATCH * NH * (SEQ / 128), 256, 0, stream>>>(
            qkvb, vtg, attn);
    } else {
        attn_mfma_fb_kernel<<<BATCH * NH * (SEQ / 128), 512, 0, stream>>>(
            qkvb, attn);
    }

    // 3) out = attn @ Wo + bo (single-pass bf16 MFMA)
    {
        dim3 grid(HIDDEN / 64, M / 128);
        gemm_out_kernel<<<grid, 256, 0, stream>>>(attn, WoT, bo, out);
    }
}

// Round 9
// 174.893 us; speedup vs baseline: 1.4303x; 1.0000x over previous
//
#include <hip/hip_runtime.h>
#include <hip/hip_bf16.h>

#define HIDDEN 1024
#define NH 16
#define BATCH 2
#define SEQ 2048

typedef __attribute__((ext_vector_type(8))) short bf16x8;
typedef __attribute__((ext_vector_type(4))) float f32x4;
typedef __attribute__((ext_vector_type(2))) uint uint2v;

__device__ __forceinline__ ushort f2bf(float f) {
    __hip_bfloat16 h = __float2bfloat16(f);
    return *reinterpret_cast<ushort*>(&h);
}
__device__ __forceinline__ float fexp2(float x) {
#if __has_builtin(__builtin_amdgcn_exp2f)
    return __builtin_amdgcn_exp2f(x);
#else
    return exp2f(x);
#endif
}
// pack trunc-bf16(a) low, trunc-bf16(b) high (1 v_perm)
__device__ __forceinline__ uint pack_bf_trunc(float a, float b) {
    return __builtin_amdgcn_perm(__float_as_uint(b), __float_as_uint(a), 0x07060302u);
}

// butterfly: (A,B) -> A' = [a0,b0,a1,b1], B' = [a2,b2,a3,b3] (16-lane rows).
__device__ __forceinline__ void bfly(uint &a, uint &b) {
#if __has_builtin(__builtin_amdgcn_permlane16_swap)
    uint2v t = __builtin_amdgcn_permlane16_swap(a, b, false, false);
    uint2v s = __builtin_amdgcn_permlane32_swap(t[0], t[1], false, false);
    a = s[0]; b = s[1];
#else
    asm volatile("v_permlane16_swap_b32 %0, %1" : "+v"(a), "+v"(b));
    asm volatile("v_permlane32_swap_b32 %0, %1" : "+v"(a), "+v"(b));
#endif
}

// async global->LDS, 16B per lane
__device__ __forceinline__ void async_copy16(const ushort* g, ushort* l) {
    __builtin_amdgcn_global_load_lds((const __attribute__((address_space(1))) void*)g,
                                     (__attribute__((address_space(3))) void*)l,
                                     16, 0, 0);
}

// ---------------------------------------------------------------------------
// Fused prep: [0,4096) x->bf16 | [4096,7168) Wqkv transpose | [7168,8192) Wo transpose
// ---------------------------------------------------------------------------
__global__ void prep_kernel(const float* __restrict__ x,
                            const float* __restrict__ Wqkv,
                            const float* __restrict__ Wo,
                            ushort* __restrict__ xb,
                            ushort* __restrict__ Wt,
                            ushort* __restrict__ WoT)
{
    __shared__ float t[32][33];
    const int bid = blockIdx.x;
    const int tid = threadIdx.x;

    if (bid < 4096) {
        int i = (bid * 256 + tid) * 4;
        float4 v = *(const float4*)(x + i);
        ushort4 w;
        w.x = f2bf(v.x); w.y = f2bf(v.y); w.z = f2bf(v.z); w.w = f2bf(v.w);
        *(ushort4*)(xb + i) = w;
        return;
    }
    const int r = tid >> 3;
    const int c = (tid & 7) * 4;
    if (bid < 7168) {
        int tt = bid - 4096;
        int k0 = (tt & 31) * 32;
        int n0 = (tt >> 5) * 32;
        const int N = 3 * HIDDEN, K = HIDDEN;
        float4 v = *(const float4*)(Wqkv + (size_t)(k0 + r) * N + n0 + c);
        t[r][c] = v.x; t[r][c + 1] = v.y; t[r][c + 2] = v.z; t[r][c + 3] = v.w;
        __syncthreads();
        ushort4 w;
        w.x = f2bf(t[c + 0][r]); w.y = f2bf(t[c + 1][r]);
        w.z = f2bf(t[c + 2][r]); w.w = f2bf(t[c + 3][r]);
        *(ushort4*)(Wt + (size_t)(n0 + r) * K + k0 + c) = w;
    } else {
        int tt = bid - 7168;
        int k0 = (tt & 31) * 32;
        int n0 = (tt >> 5) * 32;
        const int N = HIDDEN, K = HIDDEN;
        float4 v = *(const float4*)(Wo + (size_t)(k0 + r) * N + n0 + c);
        t[r][c] = v.x; t[r][c + 1] = v.y; t[r][c + 2] = v.z; t[r][c + 3] = v.w;
        __syncthreads();
        ushort4 w;
        w.x = f2bf(t[c + 0][r]); w.y = f2bf(t[c + 1][r]);
        w.z = f2bf(t[c + 2][r]); w.w = f2bf(t[c + 3][r]);
        *(ushort4*)(WoT + (size_t)(n0 + r) * K + k0 + c) = w;
    }
}

// ---------------------------------------------------------------------------
// bf16 MFMA GEMM1: qkv = x @ Wqkv^T + bias -> bf16. Q cols scaled by qscale
// (0.125*log2e -> softmax via exp2). When vt_mode, V cols (>=2048) go
// transposed + Pi-permuted into vtg[b][h][d][s'] (fused transpose_v).
// ---------------------------------------------------------------------------
__global__ __launch_bounds__(256, 3)
void gemm_mfma_bf16_kernel(const ushort* __restrict__ A,
                           const ushort* __restrict__ Bt,
                           const float* __restrict__ bias,
                           ushort* __restrict__ C, int N,
                           int qscale_cols, float qscale,
                           ushort* __restrict__ vtg, int vt_mode)
{
    constexpr int K = 1024;
    __shared__ ushort As[128 * 64];
    __shared__ ushort Bs[128 * 64];

    const int tid  = threadIdx.x;
    const int wave = tid >> 6;
    const int lane = tid & 63;
    const int l16  = lane & 15;
    const int quad = lane >> 4;
    const int wm = wave & 1, wn = wave >> 1;

    const int bm = blockIdx.y * 128;
    const int bn = blockIdx.x * 128;

    const int srow = lane >> 3;
    const int lblk = (lane & 7) ^ srow;
    const ushort* Ag = A  + (size_t)(bm + wave * 32 + srow) * K + lblk * 8;
    const ushort* Bg = Bt + (size_t)(bn + wave * 32 + srow) * K + lblk * 8;
    ushort* Asl = As + wave * 32 * 64;
    ushort* Bsl = Bs + wave * 32 * 64;

    f32x4 acc[4][4];
    #pragma unroll
    for (int i = 0; i < 4; i++)
        #pragma unroll
        for (int j = 0; j < 4; j++) acc[i][j] = (f32x4){0.f, 0.f, 0.f, 0.f};

    for (int k0 = 0; k0 < K; k0 += 64) {
        __syncthreads();
        #pragma unroll
        for (int t = 0; t < 4; t++) {
            async_copy16(Ag + (size_t)t * 8 * K + k0, Asl + t * 8 * 64);
            async_copy16(Bg + (size_t)t * 8 * K + k0, Bsl + t * 8 * 64);
        }
        __syncthreads();

        #pragma unroll
        for (int s = 0; s < 2; s++) {
            bf16x8 af[4], bfr[4];
            #pragma unroll
            for (int i = 0; i < 4; i++) {
                int m = wm * 64 + i * 16 + l16;
                int n = wn * 64 + i * 16 + l16;
                af[i]  = *(const bf16x8*)&As[m * 64 + (((s * 4 + quad) ^ (m & 7)) << 3)];
                bfr[i] = *(const bf16x8*)&Bs[n * 64 + (((s * 4 + quad) ^ (n & 7)) << 3)];
            }
            #pragma unroll
            for (int i = 0; i < 4; i++)
                #pragma unroll
                for (int j = 0; j < 4; j++)
                    acc[i][j] = __builtin_amdgcn_mfma_f32_16x16x32_bf16(af[i], bfr[j], acc[i][j], 0, 0, 0);
        }
    }

    #pragma unroll
    for (int j = 0; j < 4; j++) {
        int col = bn + wn * 64 + j * 16 + l16;
        float bv = bias[col];
        if (vt_mode && col >= 2048) {
            // V -> vtg transposed + Pi: s64 = i*16+quad*4+r; Pi(s64)=(quad*4+r)*4+i
            int dfull = col - 2048;
            int hh = dfull >> 6, dd = dfull & 63;
            int bb = bm >> 11;
            int sb = ((bm & 2047) + wm * 64) >> 6;
            ushort tmp[16];
            #pragma unroll
            for (int i = 0; i < 4; i++)
                #pragma unroll
                for (int r = 0; r < 4; r++)
                    tmp[r * 4 + i] = f2bf(acc[i][j][r] + bv);
            ushort* dst = vtg + ((size_t)((bb * NH + hh) * 64 + dd)) * SEQ
                          + sb * 64 + quad * 16;
            *(uint4*)dst = *(const uint4*)tmp;
            *(uint4*)(dst + 8) = *(const uint4*)(tmp + 8);
        } else {
            float s = (col < qscale_cols) ? qscale : 1.0f;
            #pragma unroll
            for (int i = 0; i < 4; i++) {
                int row0 = bm + wm * 64 + i * 16 + quad * 4;
                #pragma unroll
                for (int r = 0; r < 4; r++)
                    C[(size_t)(row0 + r) * N + col] = f2bf((acc[i][j][r] + bv) * s);
            }
        }
    }
}

// ---------------------------------------------------------------------------
// Output projection, single-pass bf16 MFMA: C[4096][1024]f32 = attn @ WoT^T + bo.
// ---------------------------------------------------------------------------
__global__ __launch_bounds__(256, 4)
void gemm_out_kernel(const ushort* __restrict__ A,
                     const ushort* __restrict__ Bt,
                     const float* __restrict__ bias,
                     float* __restrict__ C)
{
    constexpr int K = 1024, N = 1024;
    __shared__ ushort As[128 * 64];
    __shared__ ushort Bs[64 * 64];

    const int tid  = threadIdx.x;
    const int wave = tid >> 6;
    const int lane = tid & 63;
    const int l16  = lane & 15;
    const int quad = lane >> 4;
    const int wm = wave & 1, wn = wave >> 1;

    const int bm = blockIdx.y * 128;
    const int bn = blockIdx.x * 64;

    const int srow = lane >> 3;
    const int lblk = (lane & 7) ^ srow;
    const ushort* Ag = A  + (size_t)(bm + wave * 32 + srow) * K + lblk * 8;
    const ushort* Bg = Bt + (size_t)(bn + wave * 16 + srow) * K + lblk * 8;
    ushort* Asl = As + wave * 32 * 64;
    ushort* Bsl = Bs + wave * 16 * 64;

    f32x4 acc[4][2];
    #pragma unroll
    for (int i = 0; i < 4; i++)
        #pragma unroll
        for (int j = 0; j < 2; j++) acc[i][j] = (f32x4){0.f, 0.f, 0.f, 0.f};

    for (int k0 = 0; k0 < K; k0 += 64) {
        __syncthreads();
        #pragma unroll
        for (int t = 0; t < 4; t++)
            async_copy16(Ag + (size_t)t * 8 * K + k0, Asl + t * 8 * 64);
        #pragma unroll
        for (int t = 0; t < 2; t++)
            async_copy16(Bg + (size_t)t * 8 * K + k0, Bsl + t * 8 * 64);
        __syncthreads();

        #pragma unroll
        for (int s = 0; s < 2; s++) {
            bf16x8 af[4], bfr[2];
            #pragma unroll
            for (int i = 0; i < 4; i++) {
                int m = wm * 64 + i * 16 + l16;
                af[i] = *(const bf16x8*)&As[m * 64 + (((s * 4 + quad) ^ (m & 7)) << 3)];
            }
            #pragma unroll
            for (int j = 0; j < 2; j++) {
                int n = wn * 32 + j * 16 + l16;
                bfr[j] = *(const bf16x8*)&Bs[n * 64 + (((s * 4 + quad) ^ (n & 7)) << 3)];
            }
            #pragma unroll
            for (int i = 0; i < 4; i++)
                #pragma unroll
                for (int j = 0; j < 2; j++)
                    acc[i][j] = __builtin_amdgcn_mfma_f32_16x16x32_bf16(af[i], bfr[j], acc[i][j], 0, 0, 0);
        }
    }

    #pragma unroll
    for (int j = 0; j < 2; j++) {
        int col = bn + wn * 32 + j * 16 + l16;
        float bv = bias[col];
        #pragma unroll
        for (int i = 0; i < 4; i++) {
            int row0 = bm + wm * 64 + i * 16 + quad * 4;
            #pragma unroll
            for (int r = 0; r < 4; r++)
                C[(size_t)(row0 + r) * N + col] = acc[i][j][r] + bv;
        }
    }
}

// ---------------------------------------------------------------------------
// v14 helpers: QK (swapped), softmax->frags, PV. All register-only, identical
// math to v12/v13's verified body — only the CALL ORDER changes in v14.
// ---------------------------------------------------------------------------
__device__ __forceinline__ void qk_sub(
    const ushort* Ks, const bf16x8 (&a_q)[2][2], f32x4 (&sc)[2][4],
    int l16, int quad)
{
    #pragma unroll
    for (int nt = 0; nt < 4; nt++) {
        int key = nt * 16 + l16;
        bf16x8 bk0 = *(const bf16x8*)&Ks[key * 64 + ((quad ^ (key & 7)) << 3)];
        bf16x8 bk1 = *(const bf16x8*)&Ks[key * 64 + (((4 + quad) ^ (key & 7)) << 3)];
        #pragma unroll
        for (int mg = 0; mg < 2; mg++) {
            f32x4 a = (f32x4){0.f, 0.f, 0.f, 0.f};
            a = __builtin_amdgcn_mfma_f32_16x16x32_bf16(bk0, a_q[mg][0], a, 0, 0, 0);
            a = __builtin_amdgcn_mfma_f32_16x16x32_bf16(bk1, a_q[mg][1], a, 0, 0, 0);
            sc[mg][nt] = a;
        }
    }
}

__device__ __forceinline__ void sm_sub(const f32x4 (&sc)[2][4], bf16x8 (&ap)[2][2])
{
    #pragma unroll
    for (int mg = 0; mg < 2; mg++) {
        uint w00 = pack_bf_trunc(fexp2(sc[mg][0][0]), fexp2(sc[mg][1][0]));
        uint w01 = pack_bf_trunc(fexp2(sc[mg][0][1]), fexp2(sc[mg][1][1]));
        uint w02 = pack_bf_trunc(fexp2(sc[mg][0][2]), fexp2(sc[mg][1][2]));
        uint w03 = pack_bf_trunc(fexp2(sc[mg][0][3]), fexp2(sc[mg][1][3]));
        uint w10 = pack_bf_trunc(fexp2(sc[mg][2][0]), fexp2(sc[mg][3][0]));
        uint w11 = pack_bf_trunc(fexp2(sc[mg][2][1]), fexp2(sc[mg][3][1]));
        uint w12 = pack_bf_trunc(fexp2(sc[mg][2][2]), fexp2(sc[mg][3][2]));
        uint w13 = pack_bf_trunc(fexp2(sc[mg][2][3]), fexp2(sc[mg][3][3]));
        bfly(w00, w02);
        bfly(w01, w03);
        bfly(w10, w12);
        bfly(w11, w13);
        union { uint u[4]; bf16x8 h; } u0, u1;
        u0.u[0] = w00; u0.u[1] = w10; u0.u[2] = w01; u0.u[3] = w11;
        u1.u[0] = w02; u1.u[1] = w12; u1.u[2] = w03; u1.u[3] = w13;
        ap[mg][0] = u0.h;
        ap[mg][1] = u1.h;
    }
}

__device__ __forceinline__ void pv_sub(
    const ushort* Vs, const bf16x8 (&ap)[2][2], f32x4 (&o)[2][4],
    f32x4 (&lacc)[2], const bf16x8 &b_ones, int l16, int quad)
{
    #pragma unroll
    for (int nt = 0; nt < 4; nt++) {
        int d = nt * 16 + l16;
        bf16x8 bv0 = *(const bf16x8*)&Vs[d * 64 + ((quad ^ (d & 7)) << 3)];
        bf16x8 bv1 = *(const bf16x8*)&Vs[d * 64 + (((4 + quad) ^ (d & 7)) << 3)];
        #pragma unroll
        for (int mg = 0; mg < 2; mg++) {
            o[mg][nt] = __builtin_amdgcn_mfma_f32_16x16x32_bf16(ap[mg][0], bv0, o[mg][nt], 0, 0, 0);
            o[mg][nt] = __builtin_amdgcn_mfma_f32_16x16x32_bf16(ap[mg][1], bv1, o[mg][nt], 0, 0, 0);
        }
    }
    #pragma unroll
    for (int mg = 0; mg < 2; mg++) {
        lacc[mg] = __builtin_amdgcn_mfma_f32_16x16x32_bf16(ap[mg][0], b_ones, lacc[mg], 0, 0, 0);
        lacc[mg] = __builtin_amdgcn_mfma_f32_16x16x32_bf16(ap[mg][1], b_ones, lacc[mg], 0, 0, 0);
    }
}

// ---------------------------------------------------------------------------
// Flash attention v14: intra-wave software pipeline over v13's two sub-bodies.
// Evidence: r7 ablation marginals ADDITIVE (no phase overlap); v9 (2x TLP)
// and v13 (1/2 barriers) both null -> each SM stalls on the register result
// of the immediately preceding MFMA cluster, serializing VALU vs matrix pipe.
// v14 reorders: QK0 -> QK1 -> SM0 -> PV0 -> SM1 -> PV1. SM0 (VALU) executes
// while QK1's MFMAs drain the matrix pipe; SM1 while PV0 drains. Math is a
// pure reorder of v13's verified body (sc0/sc1 both live) -> absmax same.
// Cost: VGPR ~88->~150 (fine at 2 blocks/CU); spill tripwire = WRITE_SIZE.
// ---------------------------------------------------------------------------
__global__ __launch_bounds__(256, 2)
void attn_mfma_v14_kernel(const ushort* __restrict__ qkvb,
                          const ushort* __restrict__ vtg,
                          ushort* __restrict__ attn)
{
    // ushort layout: K[2][8192] @0 | V[2][8192] @16384  -> 64 KB
    __shared__ __align__(16) ushort smem[32768];

    const int tid  = threadIdx.x;
    const int wave = tid >> 6;
    const int lane = tid & 63;
    const int l16  = lane & 15;
    const int quad = lane >> 4;

    // XCD swizzle: xcd = bid&7 gets heads [xcd*4, xcd*4+4), all 16 qb each.
    const int obid = blockIdx.x;
    const int qb = (obid >> 3) & 15;
    const int bh = (obid & 7) * 4 + (obid >> 7);
    const int h  = bh & (NH - 1);
    const int b  = bh >> 4;

    const int qbase = qb * 128 + wave * 32;   // 32 q-rows per wave
    const int hoff  = h * 64;

    bf16x8 a_q[2][2];
    #pragma unroll
    for (int mg = 0; mg < 2; mg++) {
        int qrow = b * SEQ + qbase + mg * 16 + l16;
        const ushort* qp = qkvb + (size_t)qrow * 3072 + hoff + quad * 8;
        a_q[mg][0] = *(const bf16x8*)qp;
        a_q[mg][1] = *(const bf16x8*)(qp + 32);
    }

    f32x4 o[2][4];
    f32x4 lacc[2];
    #pragma unroll
    for (int mg = 0; mg < 2; mg++) {
        lacc[mg] = (f32x4){0.f, 0.f, 0.f, 0.f};
        #pragma unroll
        for (int nt = 0; nt < 4; nt++) o[mg][nt] = (f32x4){0.f, 0.f, 0.f, 0.f};
    }

    bf16x8 b_ones;
    #pragma unroll
    for (int j = 0; j < 8; j++) b_ones[j] = (short)0x3f80;

    const ushort* kvb    = qkvb + (size_t)b * SEQ * 3072;
    const ushort* vtg_bh = vtg + (size_t)((b * NH + h) * 64) * SEQ;

    const int srow8 = lane >> 3;
    const int gblk  = ((lane & 7) ^ srow8) << 3;
    const ushort* kg = kvb + (size_t)(wave * 16 + srow8) * 3072 + 1024 + hoff + gblk;
    const ushort* vg = vtg_bh + (size_t)(wave * 16 + srow8) * SEQ + gblk;

    ushort* k_dst = smem + wave * 1024;          // + s*4096 + c*512 + cur*8192
    ushort* v_dst = smem + 16384 + wave * 1024;  // + s*4096 + c*512 + cur*8192

    // prologue: stage tile 0 (keys 0..127) into buf 0; barrier drains vmcnt
    #pragma unroll
    for (int s = 0; s < 2; s++)
        #pragma unroll
        for (int c = 0; c < 2; c++) {
            async_copy16(kg + (size_t)(s * 64 + c * 8) * 3072,
                         k_dst + s * 4096 + c * 512);
            async_copy16(vg + (size_t)(c * 8) * SEQ + s * 64,
                         v_dst + s * 4096 + c * 512);
        }
    __syncthreads();

    int cur = 0;
    for (int t = 0; t < 16; t++) {
        const int nb = (cur ^ 1) << 13;   // next buffer offset (8192 ushorts)
        // issue next tile's K loads (drained at end-of-iter barrier)
        if (t < 15) {
            const int k0n = (t + 1) * 128;
            #pragma unroll
            for (int s = 0; s < 2; s++)
                #pragma unroll
                for (int c = 0; c < 2; c++)
                    async_copy16(kg + (size_t)(k0n + s * 64 + c * 8) * 3072,
                                 k_dst + nb + s * 4096 + c * 512);
        }

        const ushort* Kc = smem + (cur << 13);
        const ushort* Vc = smem + 16384 + (cur << 13);

        // QK for BOTH sub-tiles first: sc0 retires during QK1's issue/drain.
        f32x4 sc0[2][4], sc1[2][4];
        __builtin_amdgcn_s_setprio(1);
        qk_sub(Kc,        a_q, sc0, l16, quad);
        qk_sub(Kc + 4096, a_q, sc1, l16, quad);
        __builtin_amdgcn_s_setprio(0);

        // issue next tile's V loads (independent; drained at barrier)
        if (t < 15) {
            const int k0n = (t + 1) * 128;
            #pragma unroll
            for (int s = 0; s < 2; s++)
                #pragma unroll
                for (int c = 0; c < 2; c++)
                    async_copy16(vg + (size_t)(c * 8) * SEQ + k0n + s * 64,
                                 v_dst + nb + s * 4096 + c * 512);
        }

        // SM0 (VALU) overlaps QK1's matrix-pipe drain.
        bf16x8 ap0[2][2];
        sm_sub(sc0, ap0);

        // PV0 (MFMA) — then SM1 (VALU) overlaps PV0's drain.
        __builtin_amdgcn_s_setprio(1);
        pv_sub(Vc, ap0, o, lacc, b_ones, l16, quad);
        __builtin_amdgcn_s_setprio(0);

        bf16x8 ap1[2][2];
        sm_sub(sc1, ap1);

        __builtin_amdgcn_s_setprio(1);
        pv_sub(Vc + 4096, ap1, o, lacc, b_ones, l16, quad);
        __builtin_amdgcn_s_setprio(0);

        // single barrier per 128 keys; next tile's staged loads drained here.
        __syncthreads();
        cur ^= 1;
    }

    // epilogue: per-wave, no cross-wave combine
    #pragma unroll
    for (int mg = 0; mg < 2; mg++) {
        #pragma unroll
        for (int r = 0; r < 4; r++) {
            float inv = 1.f / lacc[mg][r];
            int row = b * SEQ + qbase + mg * 16 + quad * 4 + r;
            size_t base = (size_t)row * HIDDEN + hoff + l16;
            #pragma unroll
            for (int nt = 0; nt < 4; nt++)
                attn[base + nt * 16] = f2bf(o[mg][nt][r] * inv);
        }
    }
}

// ---------------------------------------------------------------------------
// Fallback attention (no vtg workspace): barrier kernel staging K + Pi-V.
// ---------------------------------------------------------------------------
__global__ __launch_bounds__(512, 4)
void attn_mfma_fb_kernel(const ushort* __restrict__ qkvb,
                         ushort* __restrict__ attn)
{
    __shared__ __align__(16) ushort smem[34816];

    const int tid   = threadIdx.x;
    const int wave  = tid >> 6;
    const int wavel = wave & 3;
    const int kh    = wave >> 2;
    const int lane  = tid & 63;
    const int l16   = lane & 15;
    const int quad  = lane >> 4;

    const int qb = blockIdx.x & 15;
    const int bh = blockIdx.x >> 4;
    const int h  = bh & (NH - 1);
    const int b  = bh >> 4;

    const int qbase = qb * 128;
    const int hoff  = h * 64;

    ushort* KsH = smem + kh * 4096;
    ushort* VsH = smem + 8192 + kh * 4096;
    ushort* Psw = smem + 16384 + wave * 2304;

    bf16x8 a_q[2][2];
    #pragma unroll
    for (int mg = 0; mg < 2; mg++) {
        int qrow = b * SEQ + qbase + wavel * 32 + mg * 16 + l16;
        const ushort* qp = qkvb + (size_t)qrow * 3072 + hoff + quad * 8;
        a_q[mg][0] = *(const bf16x8*)qp;
        a_q[mg][1] = *(const bf16x8*)(qp + 32);
    }

    f32x4 o[2][4];
    f32x4 lacc[2];
    #pragma unroll
    for (int mg = 0; mg < 2; mg++) {
        lacc[mg] = (f32x4){0.f, 0.f, 0.f, 0.f};
        #pragma unroll
        for (int nt = 0; nt < 4; nt++) o[mg][nt] = (f32x4){0.f, 0.f, 0.f, 0.f};
    }

    bf16x8 b_ones;
    #pragma unroll
    for (int j = 0; j < 8; j++) b_ones[j] = (short)0x3f80;

    const ushort* kvb = qkvb + (size_t)b * SEQ * 3072;

    for (int t = 0; t < 16; t++) {
        const int k0 = t * 64;
        __syncthreads();
        {
            const int tl = tid & 255;
            #pragma unroll
            for (int i = 0; i < 2; i++) {
                int key = (tl >> 3) + 32 * i;
                int blk = tl & 7;
                const ushort* ksrc = kvb + (size_t)(kh * 1024 + k0 + key) * 3072 + 1024 + hoff + blk * 8;
                uint4 kv = *(const uint4*)ksrc;
                *(uint4*)&KsH[key * 64 + ((blk ^ (key & 7)) << 3)] = kv;
                uint4 vv = *(const uint4*)(ksrc + 1024);
                const ushort* vpp = (const ushort*)&vv;
                int pk_ = (key & 15) * 4 + (key >> 4);
                #pragma unroll
                for (int j = 0; j < 8; j++) {
                    int d = blk * 8 + j;
                    VsH[d * 64 + (((pk_ >> 3) ^ (d & 7)) << 3) + (pk_ & 7)] = vpp[j];
                }
            }
        }
        __syncthreads();

        f32x4 sc[2][4];
        #pragma unroll
        for (int nt = 0; nt < 4; nt++) {
            int key = nt * 16 + l16;
            bf16x8 bk0 = *(const bf16x8*)&KsH[key * 64 + ((quad ^ (key & 7)) << 3)];
            bf16x8 bk1 = *(const bf16x8*)&KsH[key * 64 + (((4 + quad) ^ (key & 7)) << 3)];
            #pragma unroll
            for (int mg = 0; mg < 2; mg++) {
                f32x4 a = (f32x4){0.f, 0.f, 0.f, 0.f};
                a = __builtin_amdgcn_mfma_f32_16x16x32_bf16(a_q[mg][0], bk0, a, 0, 0, 0);
                a = __builtin_amdgcn_mfma_f32_16x16x32_bf16(a_q[mg][1], bk1, a, 0, 0, 0);
                sc[mg][nt] = a;
            }
        }

        #pragma unroll
        for (int mg = 0; mg < 2; mg++) {
            #pragma unroll
            for (int r = 0; r < 4; r++) {
                int q = mg * 16 + quad * 4 + r;
                uint2 pk2;
                pk2.x = pack_bf_trunc(fexp2(sc[mg][0][r]), fexp2(sc[mg][1][r]));
                pk2.y = pack_bf_trunc(fexp2(sc[mg][2][r]), fexp2(sc[mg][3][r]));
                *(uint2*)&Psw[q * 72 + l16 * 4] = pk2;
            }
        }

        asm volatile("s_waitcnt lgkmcnt(0)" ::: "memory");
        bf16x8 a_p[2][2];
        #pragma unroll
        for (int mg = 0; mg < 2; mg++) {
            a_p[mg][0] = *(const bf16x8*)&Psw[(mg * 16 + l16) * 72 + quad * 8];
            a_p[mg][1] = *(const bf16x8*)&Psw[(mg * 16 + l16) * 72 + 32 + quad * 8];
        }

        #pragma unroll
        for (int nt = 0; nt < 4; nt++) {
            int d = nt * 16 + l16;
            bf16x8 bv0 = *(const bf16x8*)&VsH[d * 64 + ((quad ^ (d & 7)) << 3)];
            bf16x8 bv1 = *(const bf16x8*)&VsH[d * 64 + (((4 + quad) ^ (d & 7)) << 3)];
            #pragma unroll
            for (int mg = 0; mg < 2; mg++) {
                o[mg][nt] = __builtin_amdgcn_mfma_f32_16x16x32_bf16(a_p[mg][0], bv0, o[mg][nt], 0, 0, 0);
                o[mg][nt] = __builtin_amdgcn_mfma_f32_16x16x32_bf16(a_p[mg][1], bv1, o[mg][nt], 0, 0, 0);
            }
        }
        #pragma unroll
        for (int mg = 0; mg < 2; mg++) {
            lacc[mg] = __builtin_amdgcn_mfma_f32_16x16x32_bf16(a_p[mg][0], b_ones, lacc[mg], 0, 0, 0);
            lacc[mg] = __builtin_amdgcn_mfma_f32_16x16x32_bf16(a_p[mg][1], b_ones, lacc[mg], 0, 0, 0);
        }
    }

    __syncthreads();
    float* osc = (float*)smem;
    float* lsc = (float*)(smem + 16384);
    const int fo = wavel * 2048 + quad * 64 + l16 * 4;
    const int fl = wavel * 512 + quad * 64 + l16 * 4;
    if (kh == 1) {
        #pragma unroll
        for (int mg = 0; mg < 2; mg++) {
            #pragma unroll
            for (int nt = 0; nt < 4; nt++)
                *(f32x4*)&osc[fo + (mg * 4 + nt) * 256] = o[mg][nt];
            *(f32x4*)&lsc[fl + mg * 256] = lacc[mg];
        }
    }
    __syncthreads();
    if (kh == 0) {
        #pragma unroll
        for (int mg = 0; mg < 2; mg++) {
            #pragma unroll
            for (int nt = 0; nt < 4; nt++)
                o[mg][nt] += *(const f32x4*)&osc[fo + (mg * 4 + nt) * 256];
            lacc[mg] += *(const f32x4*)&lsc[fl + mg * 256];
        }
        #pragma unroll
        for (int mg = 0; mg < 2; mg++) {
            #pragma unroll
            for (int r = 0; r < 4; r++) {
                float inv = 1.f / lacc[mg][r];
                int row = b * SEQ + qbase + wavel * 32 + mg * 16 + quad * 4 + r;
                size_t base = (size_t)row * HIDDEN + hoff + l16;
                #pragma unroll
                for (int nt = 0; nt < 4; nt++)
                    attn[base + nt * 16] = f2bf(o[mg][nt][r] * inv);
            }
        }
    }
}

extern "C" void kernel_launch(void* const* d_in, const int* in_sizes, int n_in,
                              void* d_out, int out_size, void* d_ws, size_t ws_size,
                              hipStream_t stream) {
    const float* x    = (const float*)d_in[0];
    const float* Wqkv = (const float*)d_in[1];
    const float* bqkv = (const float*)d_in[2];
    const float* Wo   = (const float*)d_in[3];
    const float* bo   = (const float*)d_in[4];
    float* out = (float*)d_out;

    const int M = BATCH * SEQ;                   // 4096
    const size_t MB = 1024 * 1024;

    // workspace (48 MB):
    //   [0,24) qkvb | [24,32) attn (xb overlaps: prep/GEMM1 only)
    //   [32,38) Wt (prep/GEMM1) | [38,40) WoT (prep->GEMM3) | [40,48) vtg
    char* ws = (char*)d_ws;
    ushort* qkvb = (ushort*)ws;
    ushort* attn = (ushort*)(ws + 24 * MB);
    ushort* xb   = (ushort*)(ws + 24 * MB);
    ushort* Wt   = (ushort*)(ws + 32 * MB);
    ushort* WoT  = (ushort*)(ws + 38 * MB);
    ushort* vtg  = (ushort*)(ws + 40 * MB);
    const int use_vtg = (ws_size >= 48 * MB) ? 1 : 0;

    const float qscale = 0.125f * 1.44269504088896f;   // fold log2e -> exp2 softmax

    // 0) fused preps (x->bf16, Wqkv transpose, Wo transpose)
    prep_kernel<<<8192, 256, 0, stream>>>(x, Wqkv, Wo, xb, Wt, WoT);

    // 1) qkv = (x @ Wqkv + bqkv) -> bf16; V written transposed to vtg when able
    {
        dim3 grid((3 * HIDDEN) / 128, M / 128);
        gemm_mfma_bf16_kernel<<<grid, 256, 0, stream>>>(xb, Wt, bqkv, qkvb,
                                                        3 * HIDDEN, HIDDEN, qscale,
                                                        vtg, use_vtg);
    }

    // 2) flash attention -> attn bf16
    if (use_vtg) {
        attn_mfma_v14_kernel<<<BATCH * NH * (SEQ / 128), 256, 0, stream>>>(
            qkvb, vtg, attn);
    } else {
        attn_mfma_fb_kernel<<<BATCH * NH * (SEQ / 128), 512, 0, stream>>>(
            qkvb, attn);
    }

    // 3) out = attn @ Wo + bo (single-pass bf16 MFMA)
    {
        dim3 grid(HIDDEN / 64, M / 128);
        gemm_out_kernel<<<grid, 256, 0, stream>>>(attn, WoT, bo, out);
    }
}

// Round 10
// 172.509 us; speedup vs baseline: 1.4501x; 1.0138x over previous
//
#include <hip/hip_runtime.h>
#include <hip/hip_bf16.h>

#define HIDDEN 1024
#define NH 16
#define BATCH 2
#define SEQ 2048

typedef __attribute__((ext_vector_type(8))) short bf16x8;
typedef __attribute__((ext_vector_type(4))) float f32x4;
typedef __attribute__((ext_vector_type(2))) uint uint2v;

__device__ __forceinline__ ushort f2bf(float f) {
    __hip_bfloat16 h = __float2bfloat16(f);
    return *reinterpret_cast<ushort*>(&h);
}
__device__ __forceinline__ float fexp2(float x) {
#if __has_builtin(__builtin_amdgcn_exp2f)
    return __builtin_amdgcn_exp2f(x);
#else
    return exp2f(x);
#endif
}
// pack trunc-bf16(a) low, trunc-bf16(b) high (1 v_perm)
__device__ __forceinline__ uint pack_bf_trunc(float a, float b) {
    return __builtin_amdgcn_perm(__float_as_uint(b), __float_as_uint(a), 0x07060302u);
}

// butterfly: (A,B) -> A' = [a0,b0,a1,b1], B' = [a2,b2,a3,b3] (16-lane rows).
__device__ __forceinline__ void bfly(uint &a, uint &b) {
#if __has_builtin(__builtin_amdgcn_permlane16_swap)
    uint2v t = __builtin_amdgcn_permlane16_swap(a, b, false, false);
    uint2v s = __builtin_amdgcn_permlane32_swap(t[0], t[1], false, false);
    a = s[0]; b = s[1];
#else
    asm volatile("v_permlane16_swap_b32 %0, %1" : "+v"(a), "+v"(b));
    asm volatile("v_permlane32_swap_b32 %0, %1" : "+v"(a), "+v"(b));
#endif
}

// async global->LDS, 16B per lane
__device__ __forceinline__ void async_copy16(const ushort* g, ushort* l) {
    __builtin_amdgcn_global_load_lds((const __attribute__((address_space(1))) void*)g,
                                     (__attribute__((address_space(3))) void*)l,
                                     16, 0, 0);
}

// ---------------------------------------------------------------------------
// Fused prep: [0,4096) x->bf16 | [4096,7168) Wqkv transpose | [7168,8192) Wo transpose
// ---------------------------------------------------------------------------
__global__ void prep_kernel(const float* __restrict__ x,
                            const float* __restrict__ Wqkv,
                            const float* __restrict__ Wo,
                            ushort* __restrict__ xb,
                            ushort* __restrict__ Wt,
                            ushort* __restrict__ WoT)
{
    __shared__ float t[32][33];
    const int bid = blockIdx.x;
    const int tid = threadIdx.x;

    if (bid < 4096) {
        int i = (bid * 256 + tid) * 4;
        float4 v = *(const float4*)(x + i);
        ushort4 w;
        w.x = f2bf(v.x); w.y = f2bf(v.y); w.z = f2bf(v.z); w.w = f2bf(v.w);
        *(ushort4*)(xb + i) = w;
        return;
    }
    const int r = tid >> 3;
    const int c = (tid & 7) * 4;
    if (bid < 7168) {
        int tt = bid - 4096;
        int k0 = (tt & 31) * 32;
        int n0 = (tt >> 5) * 32;
        const int N = 3 * HIDDEN, K = HIDDEN;
        float4 v = *(const float4*)(Wqkv + (size_t)(k0 + r) * N + n0 + c);
        t[r][c] = v.x; t[r][c + 1] = v.y; t[r][c + 2] = v.z; t[r][c + 3] = v.w;
        __syncthreads();
        ushort4 w;
        w.x = f2bf(t[c + 0][r]); w.y = f2bf(t[c + 1][r]);
        w.z = f2bf(t[c + 2][r]); w.w = f2bf(t[c + 3][r]);
        *(ushort4*)(Wt + (size_t)(n0 + r) * K + k0 + c) = w;
    } else {
        int tt = bid - 7168;
        int k0 = (tt & 31) * 32;
        int n0 = (tt >> 5) * 32;
        const int N = HIDDEN, K = HIDDEN;
        float4 v = *(const float4*)(Wo + (size_t)(k0 + r) * N + n0 + c);
        t[r][c] = v.x; t[r][c + 1] = v.y; t[r][c + 2] = v.z; t[r][c + 3] = v.w;
        __syncthreads();
        ushort4 w;
        w.x = f2bf(t[c + 0][r]); w.y = f2bf(t[c + 1][r]);
        w.z = f2bf(t[c + 2][r]); w.w = f2bf(t[c + 3][r]);
        *(ushort4*)(WoT + (size_t)(n0 + r) * K + k0 + c) = w;
    }
}

// ---------------------------------------------------------------------------
// OLD bf16 MFMA GEMM1 (kept for the no-vtg fallback path only).
// ---------------------------------------------------------------------------
__global__ __launch_bounds__(256, 3)
void gemm_mfma_bf16_kernel(const ushort* __restrict__ A,
                           const ushort* __restrict__ Bt,
                           const float* __restrict__ bias,
                           ushort* __restrict__ C, int N,
                           int qscale_cols, float qscale,
                           ushort* __restrict__ vtg, int vt_mode)
{
    constexpr int K = 1024;
    __shared__ ushort As[128 * 64];
    __shared__ ushort Bs[128 * 64];

    const int tid  = threadIdx.x;
    const int wave = tid >> 6;
    const int lane = tid & 63;
    const int l16  = lane & 15;
    const int quad = lane >> 4;
    const int wm = wave & 1, wn = wave >> 1;

    const int bm = blockIdx.y * 128;
    const int bn = blockIdx.x * 128;

    const int srow = lane >> 3;
    const int lblk = (lane & 7) ^ srow;
    const ushort* Ag = A  + (size_t)(bm + wave * 32 + srow) * K + lblk * 8;
    const ushort* Bg = Bt + (size_t)(bn + wave * 32 + srow) * K + lblk * 8;
    ushort* Asl = As + wave * 32 * 64;
    ushort* Bsl = Bs + wave * 32 * 64;

    f32x4 acc[4][4];
    #pragma unroll
    for (int i = 0; i < 4; i++)
        #pragma unroll
        for (int j = 0; j < 4; j++) acc[i][j] = (f32x4){0.f, 0.f, 0.f, 0.f};

    for (int k0 = 0; k0 < K; k0 += 64) {
        __syncthreads();
        #pragma unroll
        for (int t = 0; t < 4; t++) {
            async_copy16(Ag + (size_t)t * 8 * K + k0, Asl + t * 8 * 64);
            async_copy16(Bg + (size_t)t * 8 * K + k0, Bsl + t * 8 * 64);
        }
        __syncthreads();

        #pragma unroll
        for (int s = 0; s < 2; s++) {
            bf16x8 af[4], bfr[4];
            #pragma unroll
            for (int i = 0; i < 4; i++) {
                int m = wm * 64 + i * 16 + l16;
                int n = wn * 64 + i * 16 + l16;
                af[i]  = *(const bf16x8*)&As[m * 64 + (((s * 4 + quad) ^ (m & 7)) << 3)];
                bfr[i] = *(const bf16x8*)&Bs[n * 64 + (((s * 4 + quad) ^ (n & 7)) << 3)];
            }
            #pragma unroll
            for (int i = 0; i < 4; i++)
                #pragma unroll
                for (int j = 0; j < 4; j++)
                    acc[i][j] = __builtin_amdgcn_mfma_f32_16x16x32_bf16(af[i], bfr[j], acc[i][j], 0, 0, 0);
        }
    }

    #pragma unroll
    for (int j = 0; j < 4; j++) {
        int col = bn + wn * 64 + j * 16 + l16;
        float bv = bias[col];
        if (vt_mode && col >= 2048) {
            int dfull = col - 2048;
            int hh = dfull >> 6, dd = dfull & 63;
            int bb = bm >> 11;
            int sb = ((bm & 2047) + wm * 64) >> 6;
            ushort tmp[16];
            #pragma unroll
            for (int i = 0; i < 4; i++)
                #pragma unroll
                for (int r = 0; r < 4; r++)
                    tmp[r * 4 + i] = f2bf(acc[i][j][r] + bv);
            ushort* dst = vtg + ((size_t)((bb * NH + hh) * 64 + dd)) * SEQ
                          + sb * 64 + quad * 16;
            *(uint4*)dst = *(const uint4*)tmp;
            *(uint4*)(dst + 8) = *(const uint4*)(tmp + 8);
        } else {
            float s = (col < qscale_cols) ? qscale : 1.0f;
            #pragma unroll
            for (int i = 0; i < 4; i++) {
                int row0 = bm + wm * 64 + i * 16 + quad * 4;
                #pragma unroll
                for (int r = 0; r < 4; r++)
                    C[(size_t)(row0 + r) * N + col] = f2bf((acc[i][j][r] + bv) * s);
            }
        }
    }
}

// ---------------------------------------------------------------------------
// NEW GEMM1: 256x256 tile, BK=64, 512 thr (8 waves), counted-vmcnt pipeline
// (T3+T4 mechanism). Per K-step: 4 phases, each = vmcnt(4) -> s_barrier ->
// stage 1 half-tile of tile t+1 -> frag ds_reads -> 16 MFMA. vmcnt never 0
// in the loop. Stage order [Ah0,Bh0,Ah1,Bh1] vs consume order
// Q(0,0),Q(1,0),Q(0,1),Q(1,1) guarantees each phase's inputs are older than
// the 4-newest outstanding loads (vmcnt(4) window):
//   phase0 needs A0,B0 (staged t-1 p0,p1; outstanding = A1,B1 = 4)      OK
//   phase1 needs A1   (outstanding = A1,B1 + p0' = 6 -> oldest 2 done)  OK
//   phase2 needs B1   (outstanding = B1 + p0',p1' = 6 -> oldest 2 done) OK
//   phase3 needs nothing new                                            OK
// Correctness = per-wave symmetric issue + own-wave vmcnt + barrier (no
// timing assumptions). LDS 128 KB (2 slots), 1 block/CU, grid 192 (16x12,
// XCD-bijective: 192%8==0). Epilogue = verified qscale/vtg formula with
// 64-row chunks (aligned identically to the old kernel's wm*64 chunks).
// ---------------------------------------------------------------------------
template<int MH, int NHq, bool RB>
__device__ __forceinline__ void g1_phase_body(
    const ushort* Asb, const ushort* Bsb,
    bf16x8 (&af)[4][2], bf16x8 (&bfr)[2][2],
    f32x4 (&acc)[2][2][4][2], int l16, int quad, int wmp, int wnp)
{
    #pragma unroll
    for (int ip = 0; ip < 4; ip++) {
        int m = MH * 128 + wmp * 64 + ip * 16 + l16;
        #pragma unroll
        for (int ks = 0; ks < 2; ks++)
            af[ip][ks] = *(const bf16x8*)&Asb[m * 64 + (((ks * 4 + quad) ^ (m & 7)) << 3)];
    }
    if (RB) {
        #pragma unroll
        for (int jp = 0; jp < 2; jp++) {
            int n = NHq * 128 + wnp * 32 + jp * 16 + l16;
            #pragma unroll
            for (int ks = 0; ks < 2; ks++)
                bfr[jp][ks] = *(const bf16x8*)&Bsb[n * 64 + (((ks * 4 + quad) ^ (n & 7)) << 3)];
        }
    }
    __builtin_amdgcn_s_setprio(1);
    #pragma unroll
    for (int ip = 0; ip < 4; ip++)
        #pragma unroll
        for (int jp = 0; jp < 2; jp++)
            #pragma unroll
            for (int ks = 0; ks < 2; ks++)
                acc[MH][NHq][ip][jp] = __builtin_amdgcn_mfma_f32_16x16x32_bf16(
                    af[ip][ks], bfr[jp][ks], acc[MH][NHq][ip][jp], 0, 0, 0);
    __builtin_amdgcn_s_setprio(0);
}

#define G1_PHASE_SYNC()                                    \
    asm volatile("s_waitcnt vmcnt(4)" ::: "memory");       \
    __builtin_amdgcn_s_barrier();                          \
    asm volatile("" ::: "memory")

__global__ __launch_bounds__(512, 2)
void gemm1_8p_kernel(const ushort* __restrict__ A,    // xb [4096][1024]
                     const ushort* __restrict__ Bt,   // Wt [3072][1024]
                     const float* __restrict__ bias,
                     ushort* __restrict__ C,          // qkvb [4096][3072]
                     float qscale,
                     ushort* __restrict__ vtg)
{
    constexpr int Kd = 1024, Nn = 3072;
    // ushort layout: A[2][16384] @0 | B[2][16384] @32768 -> 128 KB
    __shared__ __align__(16) ushort smem[65536];

    const int tid  = threadIdx.x;
    const int lane = tid & 63;
    const int l16  = lane & 15;
    const int quad = lane >> 4;
    const int wv   = tid >> 6;
    const int wmp  = wv >> 2;     // 0..1: 64-row group within each 128-row half
    const int wnp  = wv & 3;      // 0..3: 32-col group within each 128-col half

    // XCD-bijective swizzle: 192 blocks = 8 XCD x 24
    const int obid = blockIdx.x;
    const int wg = (obid & 7) * 24 + (obid >> 3);
    const int bm = (wg / 12) * 256;
    const int bn = (wg % 12) * 256;

    // staging thread mapping: row0 = tid>>3 (0..63), blk = tid&7;
    // global col pre-swizzled so linear LDS dst (wave-uniform + lane*16B)
    // yields the XOR-swizzled layout (same scheme as all verified kernels).
    const int row0 = tid >> 3;
    const int blk  = tid & 7;
    const int swz  = ((blk ^ (row0 & 7)) << 3);
    const ushort* Ag = A  + (size_t)(bm + row0) * Kd + swz;
    const ushort* Bg = Bt + (size_t)(bn + row0) * Kd + swz;
    const int dstT = row0 * 64 + blk * 8;

    auto stageA = [&](int slot, int mh, int kt) {
        const ushort* s0 = Ag + (size_t)mh * 131072 + (size_t)kt * 64;
        ushort* d0 = smem + slot * 16384 + mh * 8192 + dstT;
        async_copy16(s0, d0);
        async_copy16(s0 + 65536, d0 + 4096);    // +64 rows
    };
    auto stageB = [&](int slot, int nh, int kt) {
        const ushort* s0 = Bg + (size_t)nh * 131072 + (size_t)kt * 64;
        ushort* d0 = smem + 32768 + slot * 16384 + nh * 8192 + dstT;
        async_copy16(s0, d0);
        async_copy16(s0 + 65536, d0 + 4096);
    };

    f32x4 acc[2][2][4][2];
    #pragma unroll
    for (int a = 0; a < 2; a++)
        #pragma unroll
        for (int b = 0; b < 2; b++)
            #pragma unroll
            for (int c = 0; c < 4; c++)
                #pragma unroll
                for (int d = 0; d < 2; d++)
                    acc[a][b][c][d] = (f32x4){0.f, 0.f, 0.f, 0.f};

    // prologue: tile 0 -> slot 0, issue order A0,B0,A1,B1 (8 loads/thread-wave)
    stageA(0, 0, 0); stageB(0, 0, 0); stageA(0, 1, 0); stageB(0, 1, 0);

    bf16x8 af[4][2], bfr[2][2];

    #pragma unroll 1
    for (int t = 0; t < 16; t++) {
        const int cur = t & 1;
        const int nxt = cur ^ 1;
        const ushort* Asb = smem + cur * 16384;
        const ushort* Bsb = smem + 32768 + cur * 16384;
        const bool st = (t < 15);
        const int kt1 = t + 1;

        // phase 0: Q(0,0) — needs Ah0,Bh0 of tile t (outside vmcnt(4) window)
        G1_PHASE_SYNC();
        if (st) stageA(nxt, 0, kt1);
        g1_phase_body<0, 0, true>(Asb, Bsb, af, bfr, acc, l16, quad, wmp, wnp);

        // phase 1: Q(1,0) — needs Ah1 (oldest beyond window)
        G1_PHASE_SYNC();
        if (st) stageB(nxt, 0, kt1);
        g1_phase_body<1, 0, false>(Asb, Bsb, af, bfr, acc, l16, quad, wmp, wnp);

        // phase 2: Q(0,1) — needs Bh1 (oldest beyond window)
        G1_PHASE_SYNC();
        if (st) stageA(nxt, 1, kt1);
        g1_phase_body<0, 1, true>(Asb, Bsb, af, bfr, acc, l16, quad, wmp, wnp);

        // phase 3: Q(1,1) — all halves already guaranteed
        G1_PHASE_SYNC();
        if (st) stageB(nxt, 1, kt1);
        g1_phase_body<1, 1, false>(Asb, Bsb, af, bfr, acc, l16, quad, wmp, wnp);
    }

    // epilogue: qscale for Q cols, vtg Pi-pack for V cols (verified formula;
    // 64-row chunks = bm + mh*128 + wmp*64, batch/sb alignment preserved).
    #pragma unroll
    for (int nh = 0; nh < 2; nh++)
        #pragma unroll
        for (int jp = 0; jp < 2; jp++) {
            int col = bn + nh * 128 + wnp * 32 + jp * 16 + l16;
            float bv = bias[col];
            if (col >= 2048) {
                int dfull = col - 2048;
                int hh = dfull >> 6, dd = dfull & 63;
                #pragma unroll
                for (int mh = 0; mh < 2; mh++) {
                    int rowchunk = bm + mh * 128 + wmp * 64;
                    int bb = rowchunk >> 11;
                    int sb = (rowchunk & 2047) >> 6;
                    ushort tmp[16];
                    #pragma unroll
                    for (int ip = 0; ip < 4; ip++)
                        #pragma unroll
                        for (int r = 0; r < 4; r++)
                            tmp[r * 4 + ip] = f2bf(acc[mh][nh][ip][jp][r] + bv);
                    ushort* dst = vtg + ((size_t)((bb * NH + hh) * 64 + dd)) * SEQ
                                  + sb * 64 + quad * 16;
                    *(uint4*)dst = *(const uint4*)tmp;
                    *(uint4*)(dst + 8) = *(const uint4*)(tmp + 8);
                }
            } else {
                float s = (col < 1024) ? qscale : 1.0f;
                #pragma unroll
                for (int mh = 0; mh < 2; mh++)
                    #pragma unroll
                    for (int ip = 0; ip < 4; ip++) {
                        int r0 = bm + mh * 128 + wmp * 64 + ip * 16 + quad * 4;
                        #pragma unroll
                        for (int r = 0; r < 4; r++)
                            C[(size_t)(r0 + r) * Nn + col] =
                                f2bf((acc[mh][nh][ip][jp][r] + bv) * s);
                    }
            }
        }
}

// ---------------------------------------------------------------------------
// Output projection, single-pass bf16 MFMA: C[4096][1024]f32 = attn @ WoT^T + bo.
// ---------------------------------------------------------------------------
__global__ __launch_bounds__(256, 4)
void gemm_out_kernel(const ushort* __restrict__ A,
                     const ushort* __restrict__ Bt,
                     const float* __restrict__ bias,
                     float* __restrict__ C)
{
    constexpr int K = 1024, N = 1024;
    __shared__ ushort As[128 * 64];
    __shared__ ushort Bs[64 * 64];

    const int tid  = threadIdx.x;
    const int wave = tid >> 6;
    const int lane = tid & 63;
    const int l16  = lane & 15;
    const int quad = lane >> 4;
    const int wm = wave & 1, wn = wave >> 1;

    const int bm = blockIdx.y * 128;
    const int bn = blockIdx.x * 64;

    const int srow = lane >> 3;
    const int lblk = (lane & 7) ^ srow;
    const ushort* Ag = A  + (size_t)(bm + wave * 32 + srow) * K + lblk * 8;
    const ushort* Bg = Bt + (size_t)(bn + wave * 16 + srow) * K + lblk * 8;
    ushort* Asl = As + wave * 32 * 64;
    ushort* Bsl = Bs + wave * 16 * 64;

    f32x4 acc[4][2];
    #pragma unroll
    for (int i = 0; i < 4; i++)
        #pragma unroll
        for (int j = 0; j < 2; j++) acc[i][j] = (f32x4){0.f, 0.f, 0.f, 0.f};

    for (int k0 = 0; k0 < K; k0 += 64) {
        __syncthreads();
        #pragma unroll
        for (int t = 0; t < 4; t++)
            async_copy16(Ag + (size_t)t * 8 * K + k0, Asl + t * 8 * 64);
        #pragma unroll
        for (int t = 0; t < 2; t++)
            async_copy16(Bg + (size_t)t * 8 * K + k0, Bsl + t * 8 * 64);
        __syncthreads();

        #pragma unroll
        for (int s = 0; s < 2; s++) {
            bf16x8 af[4], bfr[2];
            #pragma unroll
            for (int i = 0; i < 4; i++) {
                int m = wm * 64 + i * 16 + l16;
                af[i] = *(const bf16x8*)&As[m * 64 + (((s * 4 + quad) ^ (m & 7)) << 3)];
            }
            #pragma unroll
            for (int j = 0; j < 2; j++) {
                int n = wn * 32 + j * 16 + l16;
                bfr[j] = *(const bf16x8*)&Bs[n * 64 + (((s * 4 + quad) ^ (n & 7)) << 3)];
            }
            #pragma unroll
            for (int i = 0; i < 4; i++)
                #pragma unroll
                for (int j = 0; j < 2; j++)
                    acc[i][j] = __builtin_amdgcn_mfma_f32_16x16x32_bf16(af[i], bfr[j], acc[i][j], 0, 0, 0);
        }
    }

    #pragma unroll
    for (int j = 0; j < 2; j++) {
        int col = bn + wn * 32 + j * 16 + l16;
        float bv = bias[col];
        #pragma unroll
        for (int i = 0; i < 4; i++) {
            int row0 = bm + wm * 64 + i * 16 + quad * 4;
            #pragma unroll
            for (int r = 0; r < 4; r++)
                C[(size_t)(row0 + r) * N + col] = acc[i][j][r] + bv;
        }
    }
}

// ---------------------------------------------------------------------------
// v14 attn helpers (verified): QK (swapped), softmax->frags, PV.
// ---------------------------------------------------------------------------
__device__ __forceinline__ void qk_sub(
    const ushort* Ks, const bf16x8 (&a_q)[2][2], f32x4 (&sc)[2][4],
    int l16, int quad)
{
    #pragma unroll
    for (int nt = 0; nt < 4; nt++) {
        int key = nt * 16 + l16;
        bf16x8 bk0 = *(const bf16x8*)&Ks[key * 64 + ((quad ^ (key & 7)) << 3)];
        bf16x8 bk1 = *(const bf16x8*)&Ks[key * 64 + (((4 + quad) ^ (key & 7)) << 3)];
        #pragma unroll
        for (int mg = 0; mg < 2; mg++) {
            f32x4 a = (f32x4){0.f, 0.f, 0.f, 0.f};
            a = __builtin_amdgcn_mfma_f32_16x16x32_bf16(bk0, a_q[mg][0], a, 0, 0, 0);
            a = __builtin_amdgcn_mfma_f32_16x16x32_bf16(bk1, a_q[mg][1], a, 0, 0, 0);
            sc[mg][nt] = a;
        }
    }
}

__device__ __forceinline__ void sm_sub(const f32x4 (&sc)[2][4], bf16x8 (&ap)[2][2])
{
    #pragma unroll
    for (int mg = 0; mg < 2; mg++) {
        uint w00 = pack_bf_trunc(fexp2(sc[mg][0][0]), fexp2(sc[mg][1][0]));
        uint w01 = pack_bf_trunc(fexp2(sc[mg][0][1]), fexp2(sc[mg][1][1]));
        uint w02 = pack_bf_trunc(fexp2(sc[mg][0][2]), fexp2(sc[mg][1][2]));
        uint w03 = pack_bf_trunc(fexp2(sc[mg][0][3]), fexp2(sc[mg][1][3]));
        uint w10 = pack_bf_trunc(fexp2(sc[mg][2][0]), fexp2(sc[mg][3][0]));
        uint w11 = pack_bf_trunc(fexp2(sc[mg][2][1]), fexp2(sc[mg][3][1]));
        uint w12 = pack_bf_trunc(fexp2(sc[mg][2][2]), fexp2(sc[mg][3][2]));
        uint w13 = pack_bf_trunc(fexp2(sc[mg][2][3]), fexp2(sc[mg][3][3]));
        bfly(w00, w02);
        bfly(w01, w03);
        bfly(w10, w12);
        bfly(w11, w13);
        union { uint u[4]; bf16x8 h; } u0, u1;
        u0.u[0] = w00; u0.u[1] = w10; u0.u[2] = w01; u0.u[3] = w11;
        u1.u[0] = w02; u1.u[1] = w12; u1.u[2] = w03; u1.u[3] = w13;
        ap[mg][0] = u0.h;
        ap[mg][1] = u1.h;
    }
}

__device__ __forceinline__ void pv_sub(
    const ushort* Vs, const bf16x8 (&ap)[2][2], f32x4 (&o)[2][4],
    f32x4 (&lacc)[2], const bf16x8 &b_ones, int l16, int quad)
{
    #pragma unroll
    for (int nt = 0; nt < 4; nt++) {
        int d = nt * 16 + l16;
        bf16x8 bv0 = *(const bf16x8*)&Vs[d * 64 + ((quad ^ (d & 7)) << 3)];
        bf16x8 bv1 = *(const bf16x8*)&Vs[d * 64 + (((4 + quad) ^ (d & 7)) << 3)];
        #pragma unroll
        for (int mg = 0; mg < 2; mg++) {
            o[mg][nt] = __builtin_amdgcn_mfma_f32_16x16x32_bf16(ap[mg][0], bv0, o[mg][nt], 0, 0, 0);
            o[mg][nt] = __builtin_amdgcn_mfma_f32_16x16x32_bf16(ap[mg][1], bv1, o[mg][nt], 0, 0, 0);
        }
    }
    #pragma unroll
    for (int mg = 0; mg < 2; mg++) {
        lacc[mg] = __builtin_amdgcn_mfma_f32_16x16x32_bf16(ap[mg][0], b_ones, lacc[mg], 0, 0, 0);
        lacc[mg] = __builtin_amdgcn_mfma_f32_16x16x32_bf16(ap[mg][1], b_ones, lacc[mg], 0, 0, 0);
    }
}

// ---------------------------------------------------------------------------
// Flash attention v14 (best verified): KVBLK=128, intra-wave pipeline
// QK0->QK1->SM0->PV0->SM1->PV1, 1 barrier/tile, XCD swizzle. 43.0 us, 800 TF.
// ---------------------------------------------------------------------------
__global__ __launch_bounds__(256, 2)
void attn_mfma_v14_kernel(const ushort* __restrict__ qkvb,
                          const ushort* __restrict__ vtg,
                          ushort* __restrict__ attn)
{
    // ushort layout: K[2][8192] @0 | V[2][8192] @16384  -> 64 KB
    __shared__ __align__(16) ushort smem[32768];

    const int tid  = threadIdx.x;
    const int wave = tid >> 6;
    const int lane = tid & 63;
    const int l16  = lane & 15;
    const int quad = lane >> 4;

    const int obid = blockIdx.x;
    const int qb = (obid >> 3) & 15;
    const int bh = (obid & 7) * 4 + (obid >> 7);
    const int h  = bh & (NH - 1);
    const int b  = bh >> 4;

    const int qbase = qb * 128 + wave * 32;
    const int hoff  = h * 64;

    bf16x8 a_q[2][2];
    #pragma unroll
    for (int mg = 0; mg < 2; mg++) {
        int qrow = b * SEQ + qbase + mg * 16 + l16;
        const ushort* qp = qkvb + (size_t)qrow * 3072 + hoff + quad * 8;
        a_q[mg][0] = *(const bf16x8*)qp;
        a_q[mg][1] = *(const bf16x8*)(qp + 32);
    }

    f32x4 o[2][4];
    f32x4 lacc[2];
    #pragma unroll
    for (int mg = 0; mg < 2; mg++) {
        lacc[mg] = (f32x4){0.f, 0.f, 0.f, 0.f};
        #pragma unroll
        for (int nt = 0; nt < 4; nt++) o[mg][nt] = (f32x4){0.f, 0.f, 0.f, 0.f};
    }

    bf16x8 b_ones;
    #pragma unroll
    for (int j = 0; j < 8; j++) b_ones[j] = (short)0x3f80;

    const ushort* kvb    = qkvb + (size_t)b * SEQ * 3072;
    const ushort* vtg_bh = vtg + (size_t)((b * NH + h) * 64) * SEQ;

    const int srow8 = lane >> 3;
    const int gblk  = ((lane & 7) ^ srow8) << 3;
    const ushort* kg = kvb + (size_t)(wave * 16 + srow8) * 3072 + 1024 + hoff + gblk;
    const ushort* vg = vtg_bh + (size_t)(wave * 16 + srow8) * SEQ + gblk;

    ushort* k_dst = smem + wave * 1024;
    ushort* v_dst = smem + 16384 + wave * 1024;

    #pragma unroll
    for (int s = 0; s < 2; s++)
        #pragma unroll
        for (int c = 0; c < 2; c++) {
            async_copy16(kg + (size_t)(s * 64 + c * 8) * 3072,
                         k_dst + s * 4096 + c * 512);
            async_copy16(vg + (size_t)(c * 8) * SEQ + s * 64,
                         v_dst + s * 4096 + c * 512);
        }
    __syncthreads();

    int cur = 0;
    for (int t = 0; t < 16; t++) {
        const int nb = (cur ^ 1) << 13;
        if (t < 15) {
            const int k0n = (t + 1) * 128;
            #pragma unroll
            for (int s = 0; s < 2; s++)
                #pragma unroll
                for (int c = 0; c < 2; c++)
                    async_copy16(kg + (size_t)(k0n + s * 64 + c * 8) * 3072,
                                 k_dst + nb + s * 4096 + c * 512);
        }

        const ushort* Kc = smem + (cur << 13);
        const ushort* Vc = smem + 16384 + (cur << 13);

        f32x4 sc0[2][4], sc1[2][4];
        __builtin_amdgcn_s_setprio(1);
        qk_sub(Kc,        a_q, sc0, l16, quad);
        qk_sub(Kc + 4096, a_q, sc1, l16, quad);
        __builtin_amdgcn_s_setprio(0);

        if (t < 15) {
            const int k0n = (t + 1) * 128;
            #pragma unroll
            for (int s = 0; s < 2; s++)
                #pragma unroll
                for (int c = 0; c < 2; c++)
                    async_copy16(vg + (size_t)(c * 8) * SEQ + k0n + s * 64,
                                 v_dst + nb + s * 4096 + c * 512);
        }

        bf16x8 ap0[2][2];
        sm_sub(sc0, ap0);

        __builtin_amdgcn_s_setprio(1);
        pv_sub(Vc, ap0, o, lacc, b_ones, l16, quad);
        __builtin_amdgcn_s_setprio(0);

        bf16x8 ap1[2][2];
        sm_sub(sc1, ap1);

        __builtin_amdgcn_s_setprio(1);
        pv_sub(Vc + 4096, ap1, o, lacc, b_ones, l16, quad);
        __builtin_amdgcn_s_setprio(0);

        __syncthreads();
        cur ^= 1;
    }

    #pragma unroll
    for (int mg = 0; mg < 2; mg++) {
        #pragma unroll
        for (int r = 0; r < 4; r++) {
            float inv = 1.f / lacc[mg][r];
            int row = b * SEQ + qbase + mg * 16 + quad * 4 + r;
            size_t base = (size_t)row * HIDDEN + hoff + l16;
            #pragma unroll
            for (int nt = 0; nt < 4; nt++)
                attn[base + nt * 16] = f2bf(o[mg][nt][r] * inv);
        }
    }
}

// ---------------------------------------------------------------------------
// Fallback attention (no vtg workspace): barrier kernel staging K + Pi-V.
// ---------------------------------------------------------------------------
__global__ __launch_bounds__(512, 4)
void attn_mfma_fb_kernel(const ushort* __restrict__ qkvb,
                         ushort* __restrict__ attn)
{
    __shared__ __align__(16) ushort smem[34816];

    const int tid   = threadIdx.x;
    const int wave  = tid >> 6;
    const int wavel = wave & 3;
    const int kh    = wave >> 2;
    const int lane  = tid & 63;
    const int l16   = lane & 15;
    const int quad  = lane >> 4;

    const int qb = blockIdx.x & 15;
    const int bh = blockIdx.x >> 4;
    const int h  = bh & (NH - 1);
    const int b  = bh >> 4;

    const int qbase = qb * 128;
    const int hoff  = h * 64;

    ushort* KsH = smem + kh * 4096;
    ushort* VsH = smem + 8192 + kh * 4096;
    ushort* Psw = smem + 16384 + wave * 2304;

    bf16x8 a_q[2][2];
    #pragma unroll
    for (int mg = 0; mg < 2; mg++) {
        int qrow = b * SEQ + qbase + wavel * 32 + mg * 16 + l16;
        const ushort* qp = qkvb + (size_t)qrow * 3072 + hoff + quad * 8;
        a_q[mg][0] = *(const bf16x8*)qp;
        a_q[mg][1] = *(const bf16x8*)(qp + 32);
    }

    f32x4 o[2][4];
    f32x4 lacc[2];
    #pragma unroll
    for (int mg = 0; mg < 2; mg++) {
        lacc[mg] = (f32x4){0.f, 0.f, 0.f, 0.f};
        #pragma unroll
        for (int nt = 0; nt < 4; nt++) o[mg][nt] = (f32x4){0.f, 0.f, 0.f, 0.f};
    }

    bf16x8 b_ones;
    #pragma unroll
    for (int j = 0; j < 8; j++) b_ones[j] = (short)0x3f80;

    const ushort* kvb = qkvb + (size_t)b * SEQ * 3072;

    for (int t = 0; t < 16; t++) {
        const int k0 = t * 64;
        __syncthreads();
        {
            const int tl = tid & 255;
            #pragma unroll
            for (int i = 0; i < 2; i++) {
                int key = (tl >> 3) + 32 * i;
                int blk = tl & 7;
                const ushort* ksrc = kvb + (size_t)(kh * 1024 + k0 + key) * 3072 + 1024 + hoff + blk * 8;
                uint4 kv = *(const uint4*)ksrc;
                *(uint4*)&KsH[key * 64 + ((blk ^ (key & 7)) << 3)] = kv;
                uint4 vv = *(const uint4*)(ksrc + 1024);
                const ushort* vpp = (const ushort*)&vv;
                int pk_ = (key & 15) * 4 + (key >> 4);
                #pragma unroll
                for (int j = 0; j < 8; j++) {
                    int d = blk * 8 + j;
                    VsH[d * 64 + (((pk_ >> 3) ^ (d & 7)) << 3) + (pk_ & 7)] = vpp[j];
                }
            }
        }
        __syncthreads();

        f32x4 sc[2][4];
        #pragma unroll
        for (int nt = 0; nt < 4; nt++) {
            int key = nt * 16 + l16;
            bf16x8 bk0 = *(const bf16x8*)&KsH[key * 64 + ((quad ^ (key & 7)) << 3)];
            bf16x8 bk1 = *(const bf16x8*)&KsH[key * 64 + (((4 + quad) ^ (key & 7)) << 3)];
            #pragma unroll
            for (int mg = 0; mg < 2; mg++) {
                f32x4 a = (f32x4){0.f, 0.f, 0.f, 0.f};
                a = __builtin_amdgcn_mfma_f32_16x16x32_bf16(a_q[mg][0], bk0, a, 0, 0, 0);
                a = __builtin_amdgcn_mfma_f32_16x16x32_bf16(a_q[mg][1], bk1, a, 0, 0, 0);
                sc[mg][nt] = a;
            }
        }

        #pragma unroll
        for (int mg = 0; mg < 2; mg++) {
            #pragma unroll
            for (int r = 0; r < 4; r++) {
                int q = mg * 16 + quad * 4 + r;
                uint2 pk2;
                pk2.x = pack_bf_trunc(fexp2(sc[mg][0][r]), fexp2(sc[mg][1][r]));
                pk2.y = pack_bf_trunc(fexp2(sc[mg][2][r]), fexp2(sc[mg][3][r]));
                *(uint2*)&Psw[q * 72 + l16 * 4] = pk2;
            }
        }

        asm volatile("s_waitcnt lgkmcnt(0)" ::: "memory");
        bf16x8 a_p[2][2];
        #pragma unroll
        for (int mg = 0; mg < 2; mg++) {
            a_p[mg][0] = *(const bf16x8*)&Psw[(mg * 16 + l16) * 72 + quad * 8];
            a_p[mg][1] = *(const bf16x8*)&Psw[(mg * 16 + l16) * 72 + 32 + quad * 8];
        }

        #pragma unroll
        for (int nt = 0; nt < 4; nt++) {
            int d = nt * 16 + l16;
            bf16x8 bv0 = *(const bf16x8*)&VsH[d * 64 + ((quad ^ (d & 7)) << 3)];
            bf16x8 bv1 = *(const bf16x8*)&VsH[d * 64 + (((4 + quad) ^ (d & 7)) << 3)];
            #pragma unroll
            for (int mg = 0; mg < 2; mg++) {
                o[mg][nt] = __builtin_amdgcn_mfma_f32_16x16x32_bf16(a_p[mg][0], bv0, o[mg][nt], 0, 0, 0);
                o[mg][nt] = __builtin_amdgcn_mfma_f32_16x16x32_bf16(a_p[mg][1], bv1, o[mg][nt], 0, 0, 0);
            }
        }
        #pragma unroll
        for (int mg = 0; mg < 2; mg++) {
            lacc[mg] = __builtin_amdgcn_mfma_f32_16x16x32_bf16(a_p[mg][0], b_ones, lacc[mg], 0, 0, 0);
            lacc[mg] = __builtin_amdgcn_mfma_f32_16x16x32_bf16(a_p[mg][1], b_ones, lacc[mg], 0, 0, 0);
        }
    }

    __syncthreads();
    float* osc = (float*)smem;
    float* lsc = (float*)(smem + 16384);
    const int fo = wavel * 2048 + quad * 64 + l16 * 4;
    const int fl = wavel * 512 + quad * 64 + l16 * 4;
    if (kh == 1) {
        #pragma unroll
        for (int mg = 0; mg < 2; mg++) {
            #pragma unroll
            for (int nt = 0; nt < 4; nt++)
                *(f32x4*)&osc[fo + (mg * 4 + nt) * 256] = o[mg][nt];
            *(f32x4*)&lsc[fl + mg * 256] = lacc[mg];
        }
    }
    __syncthreads();
    if (kh == 0) {
        #pragma unroll
        for (int mg = 0; mg < 2; mg++) {
            #pragma unroll
            for (int nt = 0; nt < 4; nt++)
                o[mg][nt] += *(const f32x4*)&osc[fo + (mg * 4 + nt) * 256];
            lacc[mg] += *(const f32x4*)&lsc[fl + mg * 256];
        }
        #pragma unroll
        for (int mg = 0; mg < 2; mg++) {
            #pragma unroll
            for (int r = 0; r < 4; r++) {
                float inv = 1.f / lacc[mg][r];
                int row = b * SEQ + qbase + wavel * 32 + mg * 16 + quad * 4 + r;
                size_t base = (size_t)row * HIDDEN + hoff + l16;
                #pragma unroll
                for (int nt = 0; nt < 4; nt++)
                    attn[base + nt * 16] = f2bf(o[mg][nt][r] * inv);
            }
        }
    }
}

extern "C" void kernel_launch(void* const* d_in, const int* in_sizes, int n_in,
                              void* d_out, int out_size, void* d_ws, size_t ws_size,
                              hipStream_t stream) {
    const float* x    = (const float*)d_in[0];
    const float* Wqkv = (const float*)d_in[1];
    const float* bqkv = (const float*)d_in[2];
    const float* Wo   = (const float*)d_in[3];
    const float* bo   = (const float*)d_in[4];
    float* out = (float*)d_out;

    const int M = BATCH * SEQ;                   // 4096
    const size_t MB = 1024 * 1024;

    // workspace (48 MB):
    //   [0,24) qkvb | [24,32) attn (xb overlaps: prep/GEMM1 only)
    //   [32,38) Wt (prep/GEMM1) | [38,40) WoT (prep->GEMM3) | [40,48) vtg
    char* ws = (char*)d_ws;
    ushort* qkvb = (ushort*)ws;
    ushort* attn = (ushort*)(ws + 24 * MB);
    ushort* xb   = (ushort*)(ws + 24 * MB);
    ushort* Wt   = (ushort*)(ws + 32 * MB);
    ushort* WoT  = (ushort*)(ws + 38 * MB);
    ushort* vtg  = (ushort*)(ws + 40 * MB);
    const int use_vtg = (ws_size >= 48 * MB) ? 1 : 0;

    const float qscale = 0.125f * 1.44269504088896f;   // fold log2e -> exp2 softmax

    // 0) fused preps (x->bf16, Wqkv transpose, Wo transpose)
    prep_kernel<<<8192, 256, 0, stream>>>(x, Wqkv, Wo, xb, Wt, WoT);

    // 1) qkv = (x @ Wqkv + bqkv) -> bf16; V transposed to vtg.
    //    NEW: 256x256 counted-vmcnt pipeline (grid 192, 512 thr).
    if (use_vtg) {
        gemm1_8p_kernel<<<192, 512, 0, stream>>>(xb, Wt, bqkv, qkvb, qscale, vtg);
    } else {
        dim3 grid((3 * HIDDEN) / 128, M / 128);
        gemm_mfma_bf16_kernel<<<grid, 256, 0, stream>>>(xb, Wt, bqkv, qkvb,
                                                        3 * HIDDEN, HIDDEN, qscale,
                                                        vtg, 0);
    }

    // 2) flash attention -> attn bf16
    if (use_vtg) {
        attn_mfma_v14_kernel<<<BATCH * NH * (SEQ / 128), 256, 0, stream>>>(
            qkvb, vtg, attn);
    } else {
        attn_mfma_fb_kernel<<<BATCH * NH * (SEQ / 128), 512, 0, stream>>>(
            qkvb, attn);
    }

    // 3) out = attn @ Wo + bo (single-pass bf16 MFMA)
    {
        dim3 grid(HIDDEN / 64, M / 128);
        gemm_out_kernel<<<grid, 256, 0, stream>>>(attn, WoT, bo, out);
    }
}

// Round 11
// 169.952 us; speedup vs baseline: 1.4719x; 1.0150x over previous
//
#include <hip/hip_runtime.h>
#include <hip/hip_bf16.h>

#define HIDDEN 1024
#define NH 16
#define BATCH 2
#define SEQ 2048

typedef __attribute__((ext_vector_type(8))) short bf16x8;
typedef __attribute__((ext_vector_type(4))) float f32x4;
typedef __attribute__((ext_vector_type(2))) uint uint2v;

__device__ __forceinline__ ushort f2bf(float f) {
    __hip_bfloat16 h = __float2bfloat16(f);
    return *reinterpret_cast<ushort*>(&h);
}
__device__ __forceinline__ float fexp2(float x) {
#if __has_builtin(__builtin_amdgcn_exp2f)
    return __builtin_amdgcn_exp2f(x);
#else
    return exp2f(x);
#endif
}
// pack trunc-bf16(a) low, trunc-bf16(b) high (1 v_perm)
__device__ __forceinline__ uint pack_bf_trunc(float a, float b) {
    return __builtin_amdgcn_perm(__float_as_uint(b), __float_as_uint(a), 0x07060302u);
}

// butterfly: (A,B) -> A' = [a0,b0,a1,b1], B' = [a2,b2,a3,b3] (16-lane rows).
__device__ __forceinline__ void bfly(uint &a, uint &b) {
#if __has_builtin(__builtin_amdgcn_permlane16_swap)
    uint2v t = __builtin_amdgcn_permlane16_swap(a, b, false, false);
    uint2v s = __builtin_amdgcn_permlane32_swap(t[0], t[1], false, false);
    a = s[0]; b = s[1];
#else
    asm volatile("v_permlane16_swap_b32 %0, %1" : "+v"(a), "+v"(b));
    asm volatile("v_permlane32_swap_b32 %0, %1" : "+v"(a), "+v"(b));
#endif
}

// async global->LDS, 16B per lane
__device__ __forceinline__ void async_copy16(const ushort* g, ushort* l) {
    __builtin_amdgcn_global_load_lds((const __attribute__((address_space(1))) void*)g,
                                     (__attribute__((address_space(3))) void*)l,
                                     16, 0, 0);
}

// ---------------------------------------------------------------------------
// Fused prep: [0,4096) x->bf16 | [4096,7168) Wqkv transpose | [7168,8192) Wo transpose
// ---------------------------------------------------------------------------
__global__ void prep_kernel(const float* __restrict__ x,
                            const float* __restrict__ Wqkv,
                            const float* __restrict__ Wo,
                            ushort* __restrict__ xb,
                            ushort* __restrict__ Wt,
                            ushort* __restrict__ WoT)
{
    __shared__ float t[32][33];
    const int bid = blockIdx.x;
    const int tid = threadIdx.x;

    if (bid < 4096) {
        int i = (bid * 256 + tid) * 4;
        float4 v = *(const float4*)(x + i);
        ushort4 w;
        w.x = f2bf(v.x); w.y = f2bf(v.y); w.z = f2bf(v.z); w.w = f2bf(v.w);
        *(ushort4*)(xb + i) = w;
        return;
    }
    const int r = tid >> 3;
    const int c = (tid & 7) * 4;
    if (bid < 7168) {
        int tt = bid - 4096;
        int k0 = (tt & 31) * 32;
        int n0 = (tt >> 5) * 32;
        const int N = 3 * HIDDEN, K = HIDDEN;
        float4 v = *(const float4*)(Wqkv + (size_t)(k0 + r) * N + n0 + c);
        t[r][c] = v.x; t[r][c + 1] = v.y; t[r][c + 2] = v.z; t[r][c + 3] = v.w;
        __syncthreads();
        ushort4 w;
        w.x = f2bf(t[c + 0][r]); w.y = f2bf(t[c + 1][r]);
        w.z = f2bf(t[c + 2][r]); w.w = f2bf(t[c + 3][r]);
        *(ushort4*)(Wt + (size_t)(n0 + r) * K + k0 + c) = w;
    } else {
        int tt = bid - 7168;
        int k0 = (tt & 31) * 32;
        int n0 = (tt >> 5) * 32;
        const int N = HIDDEN, K = HIDDEN;
        float4 v = *(const float4*)(Wo + (size_t)(k0 + r) * N + n0 + c);
        t[r][c] = v.x; t[r][c + 1] = v.y; t[r][c + 2] = v.z; t[r][c + 3] = v.w;
        __syncthreads();
        ushort4 w;
        w.x = f2bf(t[c + 0][r]); w.y = f2bf(t[c + 1][r]);
        w.z = f2bf(t[c + 2][r]); w.w = f2bf(t[c + 3][r]);
        *(ushort4*)(WoT + (size_t)(n0 + r) * K + k0 + c) = w;
    }
}

// ---------------------------------------------------------------------------
// OLD bf16 MFMA GEMM1 (kept for the no-vtg fallback path only).
// ---------------------------------------------------------------------------
__global__ __launch_bounds__(256, 3)
void gemm_mfma_bf16_kernel(const ushort* __restrict__ A,
                           const ushort* __restrict__ Bt,
                           const float* __restrict__ bias,
                           ushort* __restrict__ C, int N,
                           int qscale_cols, float qscale,
                           ushort* __restrict__ vtg, int vt_mode)
{
    constexpr int K = 1024;
    __shared__ ushort As[128 * 64];
    __shared__ ushort Bs[128 * 64];

    const int tid  = threadIdx.x;
    const int wave = tid >> 6;
    const int lane = tid & 63;
    const int l16  = lane & 15;
    const int quad = lane >> 4;
    const int wm = wave & 1, wn = wave >> 1;

    const int bm = blockIdx.y * 128;
    const int bn = blockIdx.x * 128;

    const int srow = lane >> 3;
    const int lblk = (lane & 7) ^ srow;
    const ushort* Ag = A  + (size_t)(bm + wave * 32 + srow) * K + lblk * 8;
    const ushort* Bg = Bt + (size_t)(bn + wave * 32 + srow) * K + lblk * 8;
    ushort* Asl = As + wave * 32 * 64;
    ushort* Bsl = Bs + wave * 32 * 64;

    f32x4 acc[4][4];
    #pragma unroll
    for (int i = 0; i < 4; i++)
        #pragma unroll
        for (int j = 0; j < 4; j++) acc[i][j] = (f32x4){0.f, 0.f, 0.f, 0.f};

    for (int k0 = 0; k0 < K; k0 += 64) {
        __syncthreads();
        #pragma unroll
        for (int t = 0; t < 4; t++) {
            async_copy16(Ag + (size_t)t * 8 * K + k0, Asl + t * 8 * 64);
            async_copy16(Bg + (size_t)t * 8 * K + k0, Bsl + t * 8 * 64);
        }
        __syncthreads();

        #pragma unroll
        for (int s = 0; s < 2; s++) {
            bf16x8 af[4], bfr[4];
            #pragma unroll
            for (int i = 0; i < 4; i++) {
                int m = wm * 64 + i * 16 + l16;
                int n = wn * 64 + i * 16 + l16;
                af[i]  = *(const bf16x8*)&As[m * 64 + (((s * 4 + quad) ^ (m & 7)) << 3)];
                bfr[i] = *(const bf16x8*)&Bs[n * 64 + (((s * 4 + quad) ^ (n & 7)) << 3)];
            }
            #pragma unroll
            for (int i = 0; i < 4; i++)
                #pragma unroll
                for (int j = 0; j < 4; j++)
                    acc[i][j] = __builtin_amdgcn_mfma_f32_16x16x32_bf16(af[i], bfr[j], acc[i][j], 0, 0, 0);
        }
    }

    #pragma unroll
    for (int j = 0; j < 4; j++) {
        int col = bn + wn * 64 + j * 16 + l16;
        float bv = bias[col];
        if (vt_mode && col >= 2048) {
            int dfull = col - 2048;
            int hh = dfull >> 6, dd = dfull & 63;
            int bb = bm >> 11;
            int sb = ((bm & 2047) + wm * 64) >> 6;
            ushort tmp[16];
            #pragma unroll
            for (int i = 0; i < 4; i++)
                #pragma unroll
                for (int r = 0; r < 4; r++)
                    tmp[r * 4 + i] = f2bf(acc[i][j][r] + bv);
            ushort* dst = vtg + ((size_t)((bb * NH + hh) * 64 + dd)) * SEQ
                          + sb * 64 + quad * 16;
            *(uint4*)dst = *(const uint4*)tmp;
            *(uint4*)(dst + 8) = *(const uint4*)(tmp + 8);
        } else {
            float s = (col < qscale_cols) ? qscale : 1.0f;
            #pragma unroll
            for (int i = 0; i < 4; i++) {
                int row0 = bm + wm * 64 + i * 16 + quad * 4;
                #pragma unroll
                for (int r = 0; r < 4; r++)
                    C[(size_t)(row0 + r) * N + col] = f2bf((acc[i][j][r] + bv) * s);
            }
        }
    }
}

// ---------------------------------------------------------------------------
// GEMM1: 256x256 tile, BK=64, 512 thr (8 waves), counted-vmcnt pipeline.
// Per K-step: 4 phases, each = vmcnt(4) -> s_barrier -> stage 1 half-tile of
// tile t+1 -> frag ds_reads -> 16 MFMA. Stage order [Ah0,Bh0,Ah1,Bh1] vs
// consume order Q(0,0),Q(1,0),Q(0,1),Q(1,1) keeps each phase's inputs older
// than the 4-newest outstanding loads. ROUND-11 FIX: the final K-tile (no
// new stages) breaks that invariant — its phases 1/2 consumed data still in
// the vmcnt(4) window (latent race that passed by timing). Last iteration is
// now peeled with decreasing drains vmcnt(4)->(2)->(0)->(0).
// ---------------------------------------------------------------------------
template<int MH, int NHq, bool RB>
__device__ __forceinline__ void g1_phase_body(
    const ushort* Asb, const ushort* Bsb,
    bf16x8 (&af)[4][2], bf16x8 (&bfr)[2][2],
    f32x4 (&acc)[2][2][4][2], int l16, int quad, int wmp, int wnp)
{
    #pragma unroll
    for (int ip = 0; ip < 4; ip++) {
        int m = MH * 128 + wmp * 64 + ip * 16 + l16;
        #pragma unroll
        for (int ks = 0; ks < 2; ks++)
            af[ip][ks] = *(const bf16x8*)&Asb[m * 64 + (((ks * 4 + quad) ^ (m & 7)) << 3)];
    }
    if (RB) {
        #pragma unroll
        for (int jp = 0; jp < 2; jp++) {
            int n = NHq * 128 + wnp * 32 + jp * 16 + l16;
            #pragma unroll
            for (int ks = 0; ks < 2; ks++)
                bfr[jp][ks] = *(const bf16x8*)&Bsb[n * 64 + (((ks * 4 + quad) ^ (n & 7)) << 3)];
        }
    }
    __builtin_amdgcn_s_setprio(1);
    #pragma unroll
    for (int ip = 0; ip < 4; ip++)
        #pragma unroll
        for (int jp = 0; jp < 2; jp++)
            #pragma unroll
            for (int ks = 0; ks < 2; ks++)
                acc[MH][NHq][ip][jp] = __builtin_amdgcn_mfma_f32_16x16x32_bf16(
                    af[ip][ks], bfr[jp][ks], acc[MH][NHq][ip][jp], 0, 0, 0);
    __builtin_amdgcn_s_setprio(0);
}

#define G1_SYNC4()                                         \
    asm volatile("s_waitcnt vmcnt(4)" ::: "memory");       \
    __builtin_amdgcn_s_barrier();                          \
    asm volatile("" ::: "memory")
#define G1_SYNC2()                                         \
    asm volatile("s_waitcnt vmcnt(2)" ::: "memory");       \
    __builtin_amdgcn_s_barrier();                          \
    asm volatile("" ::: "memory")
#define G1_SYNC0()                                         \
    asm volatile("s_waitcnt vmcnt(0)" ::: "memory");       \
    __builtin_amdgcn_s_barrier();                          \
    asm volatile("" ::: "memory")

__global__ __launch_bounds__(512, 2)
void gemm1_8p_kernel(const ushort* __restrict__ A,    // xb [4096][1024]
                     const ushort* __restrict__ Bt,   // Wt [3072][1024]
                     const float* __restrict__ bias,
                     ushort* __restrict__ C,          // qkvb [4096][3072]
                     float qscale,
                     ushort* __restrict__ vtg)
{
    constexpr int Kd = 1024, Nn = 3072;
    // ushort layout: A[2][16384] @0 | B[2][16384] @32768 -> 128 KB
    __shared__ __align__(16) ushort smem[65536];

    const int tid  = threadIdx.x;
    const int lane = tid & 63;
    const int l16  = lane & 15;
    const int quad = lane >> 4;
    const int wv   = tid >> 6;
    const int wmp  = wv >> 2;     // 0..1: 64-row group within each 128-row half
    const int wnp  = wv & 3;      // 0..3: 32-col group within each 128-col half

    // XCD-bijective swizzle: 192 blocks = 8 XCD x 24
    const int obid = blockIdx.x;
    const int wg = (obid & 7) * 24 + (obid >> 3);
    const int bm = (wg / 12) * 256;
    const int bn = (wg % 12) * 256;

    const int row0 = tid >> 3;
    const int blk  = tid & 7;
    const int swz  = ((blk ^ (row0 & 7)) << 3);
    const ushort* Ag = A  + (size_t)(bm + row0) * Kd + swz;
    const ushort* Bg = Bt + (size_t)(bn + row0) * Kd + swz;
    const int dstT = row0 * 64 + blk * 8;

    auto stageA = [&](int slot, int mh, int kt) {
        const ushort* s0 = Ag + (size_t)mh * 131072 + (size_t)kt * 64;
        ushort* d0 = smem + slot * 16384 + mh * 8192 + dstT;
        async_copy16(s0, d0);
        async_copy16(s0 + 65536, d0 + 4096);    // +64 rows
    };
    auto stageB = [&](int slot, int nh, int kt) {
        const ushort* s0 = Bg + (size_t)nh * 131072 + (size_t)kt * 64;
        ushort* d0 = smem + 32768 + slot * 16384 + nh * 8192 + dstT;
        async_copy16(s0, d0);
        async_copy16(s0 + 65536, d0 + 4096);
    };

    f32x4 acc[2][2][4][2];
    #pragma unroll
    for (int a = 0; a < 2; a++)
        #pragma unroll
        for (int b = 0; b < 2; b++)
            #pragma unroll
            for (int c = 0; c < 4; c++)
                #pragma unroll
                for (int d = 0; d < 2; d++)
                    acc[a][b][c][d] = (f32x4){0.f, 0.f, 0.f, 0.f};

    // prologue: tile 0 -> slot 0, issue order A0,B0,A1,B1
    stageA(0, 0, 0); stageB(0, 0, 0); stageA(0, 1, 0); stageB(0, 1, 0);

    bf16x8 af[4][2], bfr[2][2];

    #pragma unroll 1
    for (int t = 0; t < 15; t++) {
        const int cur = t & 1;
        const int nxt = cur ^ 1;
        const ushort* Asb = smem + cur * 16384;
        const ushort* Bsb = smem + 32768 + cur * 16384;
        const int kt1 = t + 1;

        G1_SYNC4();
        stageA(nxt, 0, kt1);
        g1_phase_body<0, 0, true>(Asb, Bsb, af, bfr, acc, l16, quad, wmp, wnp);

        G1_SYNC4();
        stageB(nxt, 0, kt1);
        g1_phase_body<1, 0, false>(Asb, Bsb, af, bfr, acc, l16, quad, wmp, wnp);

        G1_SYNC4();
        stageA(nxt, 1, kt1);
        g1_phase_body<0, 1, true>(Asb, Bsb, af, bfr, acc, l16, quad, wmp, wnp);

        G1_SYNC4();
        stageB(nxt, 1, kt1);
        g1_phase_body<1, 1, false>(Asb, Bsb, af, bfr, acc, l16, quad, wmp, wnp);
    }

    // peeled t=15 (cur=1): no new stages -> decreasing drains so each phase's
    // inputs are guaranteed (outstanding at entry = A0,B0,A1,B1 of tile 15).
    {
        const ushort* Asb = smem + 16384;
        const ushort* Bsb = smem + 32768 + 16384;

        G1_SYNC4();   // drains A0,B0
        g1_phase_body<0, 0, true>(Asb, Bsb, af, bfr, acc, l16, quad, wmp, wnp);

        G1_SYNC2();   // drains A1
        g1_phase_body<1, 0, false>(Asb, Bsb, af, bfr, acc, l16, quad, wmp, wnp);

        G1_SYNC0();   // drains B1
        g1_phase_body<0, 1, true>(Asb, Bsb, af, bfr, acc, l16, quad, wmp, wnp);

        __builtin_amdgcn_s_barrier();
        g1_phase_body<1, 1, false>(Asb, Bsb, af, bfr, acc, l16, quad, wmp, wnp);
    }

    // epilogue: qscale for Q cols, vtg Pi-pack for V cols (verified formula).
    #pragma unroll
    for (int nh = 0; nh < 2; nh++)
        #pragma unroll
        for (int jp = 0; jp < 2; jp++) {
            int col = bn + nh * 128 + wnp * 32 + jp * 16 + l16;
            float bv = bias[col];
            if (col >= 2048) {
                int dfull = col - 2048;
                int hh = dfull >> 6, dd = dfull & 63;
                #pragma unroll
                for (int mh = 0; mh < 2; mh++) {
                    int rowchunk = bm + mh * 128 + wmp * 64;
                    int bb = rowchunk >> 11;
                    int sb = (rowchunk & 2047) >> 6;
                    ushort tmp[16];
                    #pragma unroll
                    for (int ip = 0; ip < 4; ip++)
                        #pragma unroll
                        for (int r = 0; r < 4; r++)
                            tmp[r * 4 + ip] = f2bf(acc[mh][nh][ip][jp][r] + bv);
                    ushort* dst = vtg + ((size_t)((bb * NH + hh) * 64 + dd)) * SEQ
                                  + sb * 64 + quad * 16;
                    *(uint4*)dst = *(const uint4*)tmp;
                    *(uint4*)(dst + 8) = *(const uint4*)(tmp + 8);
                }
            } else {
                float s = (col < 1024) ? qscale : 1.0f;
                #pragma unroll
                for (int mh = 0; mh < 2; mh++)
                    #pragma unroll
                    for (int ip = 0; ip < 4; ip++) {
                        int r0 = bm + mh * 128 + wmp * 64 + ip * 16 + quad * 4;
                        #pragma unroll
                        for (int r = 0; r < 4; r++)
                            C[(size_t)(r0 + r) * Nn + col] =
                                f2bf((acc[mh][nh][ip][jp][r] + bv) * s);
                    }
            }
        }
}

// ---------------------------------------------------------------------------
// Output projection v2: 128x64 tile, BK=64, issue-early/drain-late double
// buffer (the v13/v14-proven scheme): stage tile t+1 at iter top into the
// alternate slot, compute tile t, ONE __syncthreads() at bottom (implicit
// vmcnt(0) drain lands after ~600cy of compute instead of adjacent to the
// issue). LDS 48 KB -> 3 blocks/CU. Inner math identical to the verified
// gemm_out (absmax unchanged).
// ---------------------------------------------------------------------------
__global__ __launch_bounds__(256, 3)
void gemm_out2_kernel(const ushort* __restrict__ A,
                      const ushort* __restrict__ Bt,
                      const float* __restrict__ bias,
                      float* __restrict__ C)
{
    constexpr int K = 1024, N = 1024;
    __shared__ __align__(16) ushort As[2][128 * 64];
    __shared__ __align__(16) ushort Bs[2][64 * 64];

    const int tid  = threadIdx.x;
    const int wave = tid >> 6;
    const int lane = tid & 63;
    const int l16  = lane & 15;
    const int quad = lane >> 4;
    const int wm = wave & 1, wn = wave >> 1;

    const int bm = blockIdx.y * 128;
    const int bn = blockIdx.x * 64;

    const int srow = lane >> 3;
    const int lblk = (lane & 7) ^ srow;
    const ushort* Ag = A  + (size_t)(bm + wave * 32 + srow) * K + lblk * 8;
    const ushort* Bg = Bt + (size_t)(bn + wave * 16 + srow) * K + lblk * 8;

    auto stage = [&](int slot, int kt) {
        const int k0 = kt * 64;
        ushort* Asl = As[slot] + wave * 32 * 64;
        ushort* Bsl = Bs[slot] + wave * 16 * 64;
        #pragma unroll
        for (int t = 0; t < 4; t++)
            async_copy16(Ag + (size_t)t * 8 * K + k0, Asl + t * 8 * 64);
        #pragma unroll
        for (int t = 0; t < 2; t++)
            async_copy16(Bg + (size_t)t * 8 * K + k0, Bsl + t * 8 * 64);
    };

    f32x4 acc[4][2];
    #pragma unroll
    for (int i = 0; i < 4; i++)
        #pragma unroll
        for (int j = 0; j < 2; j++) acc[i][j] = (f32x4){0.f, 0.f, 0.f, 0.f};

    // prologue: tile 0 -> slot 0; __syncthreads drains vmcnt block-wide
    stage(0, 0);
    __syncthreads();

    for (int t = 0; t < 16; t++) {
        // issue-early: next tile into the slot everyone finished reading at
        // the END of iter t-1 (bottom barrier) — no race, no adjacent drain.
        if (t < 15) stage((t + 1) & 1, t + 1);

        const ushort* Asb = As[t & 1];
        const ushort* Bsb = Bs[t & 1];

        #pragma unroll
        for (int s = 0; s < 2; s++) {
            bf16x8 af[4], bfr[2];
            #pragma unroll
            for (int i = 0; i < 4; i++) {
                int m = wm * 64 + i * 16 + l16;
                af[i] = *(const bf16x8*)&Asb[m * 64 + (((s * 4 + quad) ^ (m & 7)) << 3)];
            }
            #pragma unroll
            for (int j = 0; j < 2; j++) {
                int n = wn * 32 + j * 16 + l16;
                bfr[j] = *(const bf16x8*)&Bsb[n * 64 + (((s * 4 + quad) ^ (n & 7)) << 3)];
            }
            __builtin_amdgcn_s_setprio(1);
            #pragma unroll
            for (int i = 0; i < 4; i++)
                #pragma unroll
                for (int j = 0; j < 2; j++)
                    acc[i][j] = __builtin_amdgcn_mfma_f32_16x16x32_bf16(af[i], bfr[j], acc[i][j], 0, 0, 0);
            __builtin_amdgcn_s_setprio(0);
        }

        // drain-late: implicit vmcnt(0) here covers tile t+1's loads with a
        // full compute body; also gates slot reuse block-wide.
        __syncthreads();
    }

    #pragma unroll
    for (int j = 0; j < 2; j++) {
        int col = bn + wn * 32 + j * 16 + l16;
        float bv = bias[col];
        #pragma unroll
        for (int i = 0; i < 4; i++) {
            int row0 = bm + wm * 64 + i * 16 + quad * 4;
            #pragma unroll
            for (int r = 0; r < 4; r++)
                C[(size_t)(row0 + r) * N + col] = acc[i][j][r] + bv;
        }
    }
}

// ---------------------------------------------------------------------------
// v14 attn helpers (verified): QK (swapped), softmax->frags, PV.
// ---------------------------------------------------------------------------
__device__ __forceinline__ void qk_sub(
    const ushort* Ks, const bf16x8 (&a_q)[2][2], f32x4 (&sc)[2][4],
    int l16, int quad)
{
    #pragma unroll
    for (int nt = 0; nt < 4; nt++) {
        int key = nt * 16 + l16;
        bf16x8 bk0 = *(const bf16x8*)&Ks[key * 64 + ((quad ^ (key & 7)) << 3)];
        bf16x8 bk1 = *(const bf16x8*)&Ks[key * 64 + (((4 + quad) ^ (key & 7)) << 3)];
        #pragma unroll
        for (int mg = 0; mg < 2; mg++) {
            f32x4 a = (f32x4){0.f, 0.f, 0.f, 0.f};
            a = __builtin_amdgcn_mfma_f32_16x16x32_bf16(bk0, a_q[mg][0], a, 0, 0, 0);
            a = __builtin_amdgcn_mfma_f32_16x16x32_bf16(bk1, a_q[mg][1], a, 0, 0, 0);
            sc[mg][nt] = a;
        }
    }
}

__device__ __forceinline__ void sm_sub(const f32x4 (&sc)[2][4], bf16x8 (&ap)[2][2])
{
    #pragma unroll
    for (int mg = 0; mg < 2; mg++) {
        uint w00 = pack_bf_trunc(fexp2(sc[mg][0][0]), fexp2(sc[mg][1][0]));
        uint w01 = pack_bf_trunc(fexp2(sc[mg][0][1]), fexp2(sc[mg][1][1]));
        uint w02 = pack_bf_trunc(fexp2(sc[mg][0][2]), fexp2(sc[mg][1][2]));
        uint w03 = pack_bf_trunc(fexp2(sc[mg][0][3]), fexp2(sc[mg][1][3]));
        uint w10 = pack_bf_trunc(fexp2(sc[mg][2][0]), fexp2(sc[mg][3][0]));
        uint w11 = pack_bf_trunc(fexp2(sc[mg][2][1]), fexp2(sc[mg][3][1]));
        uint w12 = pack_bf_trunc(fexp2(sc[mg][2][2]), fexp2(sc[mg][3][2]));
        uint w13 = pack_bf_trunc(fexp2(sc[mg][2][3]), fexp2(sc[mg][3][3]));
        bfly(w00, w02);
        bfly(w01, w03);
        bfly(w10, w12);
        bfly(w11, w13);
        union { uint u[4]; bf16x8 h; } u0, u1;
        u0.u[0] = w00; u0.u[1] = w10; u0.u[2] = w01; u0.u[3] = w11;
        u1.u[0] = w02; u1.u[1] = w12; u1.u[2] = w03; u1.u[3] = w13;
        ap[mg][0] = u0.h;
        ap[mg][1] = u1.h;
    }
}

__device__ __forceinline__ void pv_sub(
    const ushort* Vs, const bf16x8 (&ap)[2][2], f32x4 (&o)[2][4],
    f32x4 (&lacc)[2], const bf16x8 &b_ones, int l16, int quad)
{
    #pragma unroll
    for (int nt = 0; nt < 4; nt++) {
        int d = nt * 16 + l16;
        bf16x8 bv0 = *(const bf16x8*)&Vs[d * 64 + ((quad ^ (d & 7)) << 3)];
        bf16x8 bv1 = *(const bf16x8*)&Vs[d * 64 + (((4 + quad) ^ (d & 7)) << 3)];
        #pragma unroll
        for (int mg = 0; mg < 2; mg++) {
            o[mg][nt] = __builtin_amdgcn_mfma_f32_16x16x32_bf16(ap[mg][0], bv0, o[mg][nt], 0, 0, 0);
            o[mg][nt] = __builtin_amdgcn_mfma_f32_16x16x32_bf16(ap[mg][1], bv1, o[mg][nt], 0, 0, 0);
        }
    }
    #pragma unroll
    for (int mg = 0; mg < 2; mg++) {
        lacc[mg] = __builtin_amdgcn_mfma_f32_16x16x32_bf16(ap[mg][0], b_ones, lacc[mg], 0, 0, 0);
        lacc[mg] = __builtin_amdgcn_mfma_f32_16x16x32_bf16(ap[mg][1], b_ones, lacc[mg], 0, 0, 0);
    }
}

// ---------------------------------------------------------------------------
// Flash attention v14 (best verified): KVBLK=128, intra-wave pipeline
// QK0->QK1->SM0->PV0->SM1->PV1, 1 barrier/tile, XCD swizzle. 43.0 us, 800 TF.
// ---------------------------------------------------------------------------
__global__ __launch_bounds__(256, 2)
void attn_mfma_v14_kernel(const ushort* __restrict__ qkvb,
                          const ushort* __restrict__ vtg,
                          ushort* __restrict__ attn)
{
    // ushort layout: K[2][8192] @0 | V[2][8192] @16384  -> 64 KB
    __shared__ __align__(16) ushort smem[32768];

    const int tid  = threadIdx.x;
    const int wave = tid >> 6;
    const int lane = tid & 63;
    const int l16  = lane & 15;
    const int quad = lane >> 4;

    const int obid = blockIdx.x;
    const int qb = (obid >> 3) & 15;
    const int bh = (obid & 7) * 4 + (obid >> 7);
    const int h  = bh & (NH - 1);
    const int b  = bh >> 4;

    const int qbase = qb * 128 + wave * 32;
    const int hoff  = h * 64;

    bf16x8 a_q[2][2];
    #pragma unroll
    for (int mg = 0; mg < 2; mg++) {
        int qrow = b * SEQ + qbase + mg * 16 + l16;
        const ushort* qp = qkvb + (size_t)qrow * 3072 + hoff + quad * 8;
        a_q[mg][0] = *(const bf16x8*)qp;
        a_q[mg][1] = *(const bf16x8*)(qp + 32);
    }

    f32x4 o[2][4];
    f32x4 lacc[2];
    #pragma unroll
    for (int mg = 0; mg < 2; mg++) {
        lacc[mg] = (f32x4){0.f, 0.f, 0.f, 0.f};
        #pragma unroll
        for (int nt = 0; nt < 4; nt++) o[mg][nt] = (f32x4){0.f, 0.f, 0.f, 0.f};
    }

    bf16x8 b_ones;
    #pragma unroll
    for (int j = 0; j < 8; j++) b_ones[j] = (short)0x3f80;

    const ushort* kvb    = qkvb + (size_t)b * SEQ * 3072;
    const ushort* vtg_bh = vtg + (size_t)((b * NH + h) * 64) * SEQ;

    const int srow8 = lane >> 3;
    const int gblk  = ((lane & 7) ^ srow8) << 3;
    const ushort* kg = kvb + (size_t)(wave * 16 + srow8) * 3072 + 1024 + hoff + gblk;
    const ushort* vg = vtg_bh + (size_t)(wave * 16 + srow8) * SEQ + gblk;

    ushort* k_dst = smem + wave * 1024;
    ushort* v_dst = smem + 16384 + wave * 1024;

    #pragma unroll
    for (int s = 0; s < 2; s++)
        #pragma unroll
        for (int c = 0; c < 2; c++) {
            async_copy16(kg + (size_t)(s * 64 + c * 8) * 3072,
                         k_dst + s * 4096 + c * 512);
            async_copy16(vg + (size_t)(c * 8) * SEQ + s * 64,
                         v_dst + s * 4096 + c * 512);
        }
    __syncthreads();

    int cur = 0;
    for (int t = 0; t < 16; t++) {
        const int nb = (cur ^ 1) << 13;
        if (t < 15) {
            const int k0n = (t + 1) * 128;
            #pragma unroll
            for (int s = 0; s < 2; s++)
                #pragma unroll
                for (int c = 0; c < 2; c++)
                    async_copy16(kg + (size_t)(k0n + s * 64 + c * 8) * 3072,
                                 k_dst + nb + s * 4096 + c * 512);
        }

        const ushort* Kc = smem + (cur << 13);
        const ushort* Vc = smem + 16384 + (cur << 13);

        f32x4 sc0[2][4], sc1[2][4];
        __builtin_amdgcn_s_setprio(1);
        qk_sub(Kc,        a_q, sc0, l16, quad);
        qk_sub(Kc + 4096, a_q, sc1, l16, quad);
        __builtin_amdgcn_s_setprio(0);

        if (t < 15) {
            const int k0n = (t + 1) * 128;
            #pragma unroll
            for (int s = 0; s < 2; s++)
                #pragma unroll
                for (int c = 0; c < 2; c++)
                    async_copy16(vg + (size_t)(c * 8) * SEQ + k0n + s * 64,
                                 v_dst + nb + s * 4096 + c * 512);
        }

        bf16x8 ap0[2][2];
        sm_sub(sc0, ap0);

        __builtin_amdgcn_s_setprio(1);
        pv_sub(Vc, ap0, o, lacc, b_ones, l16, quad);
        __builtin_amdgcn_s_setprio(0);

        bf16x8 ap1[2][2];
        sm_sub(sc1, ap1);

        __builtin_amdgcn_s_setprio(1);
        pv_sub(Vc + 4096, ap1, o, lacc, b_ones, l16, quad);
        __builtin_amdgcn_s_setprio(0);

        __syncthreads();
        cur ^= 1;
    }

    #pragma unroll
    for (int mg = 0; mg < 2; mg++) {
        #pragma unroll
        for (int r = 0; r < 4; r++) {
            float inv = 1.f / lacc[mg][r];
            int row = b * SEQ + qbase + mg * 16 + quad * 4 + r;
            size_t base = (size_t)row * HIDDEN + hoff + l16;
            #pragma unroll
            for (int nt = 0; nt < 4; nt++)
                attn[base + nt * 16] = f2bf(o[mg][nt][r] * inv);
        }
    }
}

// ---------------------------------------------------------------------------
// Fallback attention (no vtg workspace): barrier kernel staging K + Pi-V.
// ---------------------------------------------------------------------------
__global__ __launch_bounds__(512, 4)
void attn_mfma_fb_kernel(const ushort* __restrict__ qkvb,
                         ushort* __restrict__ attn)
{
    __shared__ __align__(16) ushort smem[34816];

    const int tid   = threadIdx.x;
    const int wave  = tid >> 6;
    const int wavel = wave & 3;
    const int kh    = wave >> 2;
    const int lane  = tid & 63;
    const int l16   = lane & 15;
    const int quad  = lane >> 4;

    const int qb = blockIdx.x & 15;
    const int bh = blockIdx.x >> 4;
    const int h  = bh & (NH - 1);
    const int b  = bh >> 4;

    const int qbase = qb * 128;
    const int hoff  = h * 64;

    ushort* KsH = smem + kh * 4096;
    ushort* VsH = smem + 8192 + kh * 4096;
    ushort* Psw = smem + 16384 + wave * 2304;

    bf16x8 a_q[2][2];
    #pragma unroll
    for (int mg = 0; mg < 2; mg++) {
        int qrow = b * SEQ + qbase + wavel * 32 + mg * 16 + l16;
        const ushort* qp = qkvb + (size_t)qrow * 3072 + hoff + quad * 8;
        a_q[mg][0] = *(const bf16x8*)qp;
        a_q[mg][1] = *(const bf16x8*)(qp + 32);
    }

    f32x4 o[2][4];
    f32x4 lacc[2];
    #pragma unroll
    for (int mg = 0; mg < 2; mg++) {
        lacc[mg] = (f32x4){0.f, 0.f, 0.f, 0.f};
        #pragma unroll
        for (int nt = 0; nt < 4; nt++) o[mg][nt] = (f32x4){0.f, 0.f, 0.f, 0.f};
    }

    bf16x8 b_ones;
    #pragma unroll
    for (int j = 0; j < 8; j++) b_ones[j] = (short)0x3f80;

    const ushort* kvb = qkvb + (size_t)b * SEQ * 3072;

    for (int t = 0; t < 16; t++) {
        const int k0 = t * 64;
        __syncthreads();
        {
            const int tl = tid & 255;
            #pragma unroll
            for (int i = 0; i < 2; i++) {
                int key = (tl >> 3) + 32 * i;
                int blk = tl & 7;
                const ushort* ksrc = kvb + (size_t)(kh * 1024 + k0 + key) * 3072 + 1024 + hoff + blk * 8;
                uint4 kv = *(const uint4*)ksrc;
                *(uint4*)&KsH[key * 64 + ((blk ^ (key & 7)) << 3)] = kv;
                uint4 vv = *(const uint4*)(ksrc + 1024);
                const ushort* vpp = (const ushort*)&vv;
                int pk_ = (key & 15) * 4 + (key >> 4);
                #pragma unroll
                for (int j = 0; j < 8; j++) {
                    int d = blk * 8 + j;
                    VsH[d * 64 + (((pk_ >> 3) ^ (d & 7)) << 3) + (pk_ & 7)] = vpp[j];
                }
            }
        }
        __syncthreads();

        f32x4 sc[2][4];
        #pragma unroll
        for (int nt = 0; nt < 4; nt++) {
            int key = nt * 16 + l16;
            bf16x8 bk0 = *(const bf16x8*)&KsH[key * 64 + ((quad ^ (key & 7)) << 3)];
            bf16x8 bk1 = *(const bf16x8*)&KsH[key * 64 + (((4 + quad) ^ (key & 7)) << 3)];
            #pragma unroll
            for (int mg = 0; mg < 2; mg++) {
                f32x4 a = (f32x4){0.f, 0.f, 0.f, 0.f};
                a = __builtin_amdgcn_mfma_f32_16x16x32_bf16(a_q[mg][0], bk0, a, 0, 0, 0);
                a = __builtin_amdgcn_mfma_f32_16x16x32_bf16(a_q[mg][1], bk1, a, 0, 0, 0);
                sc[mg][nt] = a;
            }
        }

        #pragma unroll
        for (int mg = 0; mg < 2; mg++) {
            #pragma unroll
            for (int r = 0; r < 4; r++) {
                int q = mg * 16 + quad * 4 + r;
                uint2 pk2;
                pk2.x = pack_bf_trunc(fexp2(sc[mg][0][r]), fexp2(sc[mg][1][r]));
                pk2.y = pack_bf_trunc(fexp2(sc[mg][2][r]), fexp2(sc[mg][3][r]));
                *(uint2*)&Psw[q * 72 + l16 * 4] = pk2;
            }
        }

        asm volatile("s_waitcnt lgkmcnt(0)" ::: "memory");
        bf16x8 a_p[2][2];
        #pragma unroll
        for (int mg = 0; mg < 2; mg++) {
            a_p[mg][0] = *(const bf16x8*)&Psw[(mg * 16 + l16) * 72 + quad * 8];
            a_p[mg][1] = *(const bf16x8*)&Psw[(mg * 16 + l16) * 72 + 32 + quad * 8];
        }

        #pragma unroll
        for (int nt = 0; nt < 4; nt++) {
            int d = nt * 16 + l16;
            bf16x8 bv0 = *(const bf16x8*)&VsH[d * 64 + ((quad ^ (d & 7)) << 3)];
            bf16x8 bv1 = *(const bf16x8*)&VsH[d * 64 + (((4 + quad) ^ (d & 7)) << 3)];
            #pragma unroll
            for (int mg = 0; mg < 2; mg++) {
                o[mg][nt] = __builtin_amdgcn_mfma_f32_16x16x32_bf16(a_p[mg][0], bv0, o[mg][nt], 0, 0, 0);
                o[mg][nt] = __builtin_amdgcn_mfma_f32_16x16x32_bf16(a_p[mg][1], bv1, o[mg][nt], 0, 0, 0);
            }
        }
        #pragma unroll
        for (int mg = 0; mg < 2; mg++) {
            lacc[mg] = __builtin_amdgcn_mfma_f32_16x16x32_bf16(a_p[mg][0], b_ones, lacc[mg], 0, 0, 0);
            lacc[mg] = __builtin_amdgcn_mfma_f32_16x16x32_bf16(a_p[mg][1], b_ones, lacc[mg], 0, 0, 0);
        }
    }

    __syncthreads();
    float* osc = (float*)smem;
    float* lsc = (float*)(smem + 16384);
    const int fo = wavel * 2048 + quad * 64 + l16 * 4;
    const int fl = wavel * 512 + quad * 64 + l16 * 4;
    if (kh == 1) {
        #pragma unroll
        for (int mg = 0; mg < 2; mg++) {
            #pragma unroll
            for (int nt = 0; nt < 4; nt++)
                *(f32x4*)&osc[fo + (mg * 4 + nt) * 256] = o[mg][nt];
            *(f32x4*)&lsc[fl + mg * 256] = lacc[mg];
        }
    }
    __syncthreads();
    if (kh == 0) {
        #pragma unroll
        for (int mg = 0; mg < 2; mg++) {
            #pragma unroll
            for (int nt = 0; nt < 4; nt++)
                o[mg][nt] += *(const f32x4*)&osc[fo + (mg * 4 + nt) * 256];
            lacc[mg] += *(const f32x4*)&lsc[fl + mg * 256];
        }
        #pragma unroll
        for (int mg = 0; mg < 2; mg++) {
            #pragma unroll
            for (int r = 0; r < 4; r++) {
                float inv = 1.f / lacc[mg][r];
                int row = b * SEQ + qbase + wavel * 32 + mg * 16 + quad * 4 + r;
                size_t base = (size_t)row * HIDDEN + hoff + l16;
                #pragma unroll
                for (int nt = 0; nt < 4; nt++)
                    attn[base + nt * 16] = f2bf(o[mg][nt][r] * inv);
            }
        }
    }
}

extern "C" void kernel_launch(void* const* d_in, const int* in_sizes, int n_in,
                              void* d_out, int out_size, void* d_ws, size_t ws_size,
                              hipStream_t stream) {
    const float* x    = (const float*)d_in[0];
    const float* Wqkv = (const float*)d_in[1];
    const float* bqkv = (const float*)d_in[2];
    const float* Wo   = (const float*)d_in[3];
    const float* bo   = (const float*)d_in[4];
    float* out = (float*)d_out;

    const int M = BATCH * SEQ;                   // 4096
    const size_t MB = 1024 * 1024;

    // workspace (48 MB):
    //   [0,24) qkvb | [24,32) attn (xb overlaps: prep/GEMM1 only)
    //   [32,38) Wt (prep/GEMM1) | [38,40) WoT (prep->GEMM3) | [40,48) vtg
    char* ws = (char*)d_ws;
    ushort* qkvb = (ushort*)ws;
    ushort* attn = (ushort*)(ws + 24 * MB);
    ushort* xb   = (ushort*)(ws + 24 * MB);
    ushort* Wt   = (ushort*)(ws + 32 * MB);
    ushort* WoT  = (ushort*)(ws + 38 * MB);
    ushort* vtg  = (ushort*)(ws + 40 * MB);
    const int use_vtg = (ws_size >= 48 * MB) ? 1 : 0;

    const float qscale = 0.125f * 1.44269504088896f;   // fold log2e -> exp2 softmax

    // 0) fused preps (x->bf16, Wqkv transpose, Wo transpose)
    prep_kernel<<<8192, 256, 0, stream>>>(x, Wqkv, Wo, xb, Wt, WoT);

    // 1) qkv = (x @ Wqkv + bqkv) -> bf16; V transposed to vtg.
    if (use_vtg) {
        gemm1_8p_kernel<<<192, 512, 0, stream>>>(xb, Wt, bqkv, qkvb, qscale, vtg);
    } else {
        dim3 grid((3 * HIDDEN) / 128, M / 128);
        gemm_mfma_bf16_kernel<<<grid, 256, 0, stream>>>(xb, Wt, bqkv, qkvb,
                                                        3 * HIDDEN, HIDDEN, qscale,
                                                        vtg, 0);
    }

    // 2) flash attention -> attn bf16
    if (use_vtg) {
        attn_mfma_v14_kernel<<<BATCH * NH * (SEQ / 128), 256, 0, stream>>>(
            qkvb, vtg, attn);
    } else {
        attn_mfma_fb_kernel<<<BATCH * NH * (SEQ / 128), 512, 0, stream>>>(
            qkvb, attn);
    }

    // 3) out = attn @ Wo + bo (issue-early/drain-late double-buffered)
    {
        dim3 grid(HIDDEN / 64, M / 128);
        gemm_out2_kernel<<<grid, 256, 0, stream>>>(attn, WoT, bo, out);
    }
}